// Round 6
// baseline (289.789 us; speedup 1.0000x reference)
//
#include <hip/hip_runtime.h>
#include <math.h>

#define BB 4
#define NN 4096
#define KNBR 20
#define BN (BB * NN)
#define HALF 2048          // summed indices per block-half

__device__ __forceinline__ float gelu_f(float x) {
    return 0.5f * x * (1.0f + erff(x * 0.70710678118654752440f));
}

// ---------------- K0: per-point precompute: q, k, packed (x,y,z,|p|^2) ----
__global__ void k0_prep(const float* __restrict__ xyz,
                        const float* __restrict__ w_q, const float* __restrict__ g_q, const float* __restrict__ b_q,
                        const float* __restrict__ w_k, const float* __restrict__ g_k, const float* __restrict__ b_k,
                        float* __restrict__ qv, float* __restrict__ kv, float4* __restrict__ pts4) {
    int t = blockIdx.x * blockDim.x + threadIdx.x;
    if (t >= BN) return;
    int b = t / NN, n = t % NN;
    const float* base = xyz + (size_t)b * 3 * NN;
    float x = base[n], y = base[NN + n], z = base[2 * NN + n];
    float sq = x * x + y * y + z * z;
    const float invs = rsqrtf(1.0f + 1e-5f);
    float qr = x * (w_q[0] + w_q[3]) + y * (w_q[1] + w_q[4]) + z * (w_q[2] + w_q[5]);
    float kr = x * (w_k[0] + w_k[3]) + y * (w_k[1] + w_k[4]) + z * (w_k[2] + w_k[5]);
    qv[t] = qr * (g_q[0] * invs) + b_q[0];
    kv[t] = kr * (g_k[0] * invs) + b_k[0];
    pts4[t] = make_float4(x, y, z, sq);
}

// ---------------- P1: kd partials (LDS-staged broadcast) ------------------
__global__ __launch_bounds__(1024, 8)
void p1_kd(const float4* __restrict__ pts4, float* __restrict__ part) {
    __shared__ float4 stg[1024];
    __shared__ float s_red[16][64];
    int tid = threadIdx.x;
    int wave = __builtin_amdgcn_readfirstlane(tid >> 6);
    int lane = tid & 63;
    int g = blockIdx.x >> 1, half = blockIdx.x & 1;
    int b = g >> 6;
    const float4* src = pts4 + (size_t)b * NN + (size_t)half * HALF;
    float4 fr = pts4[g * 64 + lane];
    float acc = 0.f;
    float4 pre = src[tid];                 // prefetch chunk 0 (1024 recs x 16B)
    for (int c = 0; c < 2; ++c) {
        __syncthreads();
        stg[tid] = pre;
        __syncthreads();
        if (c < 1) pre = src[1024 + tid];
        int j0 = wave * 64;
        #pragma unroll 8
        for (int j = j0; j < j0 + 64; ++j) {
            float4 fc = stg[j];
            float dot = fr.x * fc.x + fr.y * fc.y + fr.z * fc.z;
            float d = fmaf(-2.0f, dot, fr.w) + fc.w;
            acc += __expf(-50.0f * d);
        }
    }
    s_red[wave][lane] = acc;
    __syncthreads();
    if (tid < 64) {
        float s = 0.f;
        #pragma unroll
        for (int w = 0; w < 16; ++w) s += s_red[w][tid];
        part[half * BN + g * 64 + tid] = s;
    }
}

// ---------------- K2: reduce kd + per-batch max -> radius; write recB -----
// recB[2n] = {x,y,z,sq}; recB[2n+1] = {k, q, rad, 0}
__global__ void k2_radius(const float* __restrict__ part, const float4* __restrict__ pts4,
                          const float* __restrict__ qv, const float* __restrict__ kv,
                          float* __restrict__ radius, float4* __restrict__ recB) {
    int b = blockIdx.x;
    int t = threadIdx.x;   // 1024
    float kdv[4];
    float mx = -1e30f;
    #pragma unroll
    for (int j = 0; j < 4; ++j) {
        int n = b * NN + j * 1024 + t;
        kdv[j] = part[n] + part[BN + n];
        mx = fmaxf(mx, kdv[j]);
    }
    __shared__ float red[1024];
    red[t] = mx;
    __syncthreads();
    for (int s = 512; s > 0; s >>= 1) {
        if (t < s) red[t] = fmaxf(red[t], red[t + s]);
        __syncthreads();
    }
    float kmax = red[0];
    #pragma unroll
    for (int j = 0; j < 4; ++j) {
        int n = b * NN + j * 1024 + t;
        float rad = 0.1f + 0.1f * (kdv[j] / (kmax + 1e-9f));
        radius[n] = rad;
        recB[2 * n] = pts4[n];
        recB[2 * n + 1] = make_float4(kv[n], qv[n], rad, 0.f);
    }
}

// ---------------- P3: Z partials (LDS-staged) + k7 neighbor scan ----------
__global__ __launch_bounds__(1024, 8)
void p3_Zk7(const float4* __restrict__ recB, const float4* __restrict__ pts4,
            const float* __restrict__ radius, float* __restrict__ part,
            int* __restrict__ idxg) {
    __shared__ float4 stg[1024];
    __shared__ float s_red[16][64];
    int tid = threadIdx.x;
    int wave = __builtin_amdgcn_readfirstlane(tid >> 6);
    int lane = tid & 63;
    int g = blockIdx.x >> 1, half = blockIdx.x & 1;
    int b = g >> 6;
    const float4* src = recB + ((size_t)b * NN + (size_t)half * HALF) * 2;
    int row = g * 64 + lane;
    float4 fr = recB[2 * row];
    float4 rowa = recB[2 * row + 1];
    float qn = rowa.y, rad = rowa.z;
    float acc = 0.f;
    float4 pre = src[tid];                 // chunk = 512 recs x 32B = 1024 float4
    for (int c = 0; c < 4; ++c) {
        __syncthreads();
        stg[tid] = pre;
        __syncthreads();
        if (c < 3) pre = src[(c + 1) * 1024 + tid];
        int j0 = wave * 32;
        #pragma unroll 8
        for (int j = j0; j < j0 + 32; ++j) {
            float4 fc = stg[2 * j];
            float4 an = stg[2 * j + 1];    // {k, q, rad, 0}
            float dot = fr.x * fc.x + fr.y * fc.y + fr.z * fc.z;
            float d = fmaf(-2.0f, dot, fr.w) + fc.w;
            float e = __expf(qn * an.x);
            acc += (d < rad) ? e : 0.f;
        }
    }
    s_red[wave][lane] = acc;
    __syncthreads();
    if (tid < 64) {
        float s = 0.f;
        #pragma unroll
        for (int w = 0; w < 16; ++w) s += s_red[w][tid];
        part[half * BN + g * 64 + tid] = s;
    }
    // k7: first-20-by-index in-ball neighbors; 2 rows per wave
    int gw = blockIdx.x * 16 + wave;
    for (int rr = 0; rr < 2; ++rr) {
        int row7 = gw * 2 + rr;
        int b7 = row7 / NN;
        const float4* p7 = pts4 + (size_t)b7 * NN;
        float4 f7 = pts4[row7];
        float rad7 = radius[row7];
        int total = 0, firstm = 0;
        bool have = false;
        unsigned long long lmask = (1ULL << lane) - 1ULL;
        for (int i = 0; i < NN / 64 && total < KNBR; ++i) {
            int m = i * 64 + lane;
            float4 fc = p7[m];
            float dot = f7.x * fc.x + f7.y * fc.y + f7.z * fc.z;
            float d = fmaf(-2.0f, dot, f7.w) + fc.w;
            bool inb = !(d > rad7);   // dist <= radius
            unsigned long long mask = __ballot(inb);
            if (!have && mask != 0ULL) {
                int src7 = __ffsll(mask) - 1;
                firstm = __shfl(m, src7);
                have = true;
            }
            int pos = total + (int)__popcll(mask & lmask);
            if (inb && pos < KNBR) idxg[(size_t)row7 * KNBR + pos] = m;
            total += (int)__popcll(mask);
        }
        if (total < KNBR && lane >= total && lane < KNBR)
            idxg[(size_t)row7 * KNBR + lane] = firstm;
    }
}

// ---------------- R3: Z = sum; recC = {pts4},{q, rad, lnZ, 0} -------------
__global__ void r3_Z(const float* __restrict__ part, const float4* __restrict__ pts4,
                     const float* __restrict__ qv, const float* __restrict__ radius,
                     float* __restrict__ Z, float4* __restrict__ recC) {
    int t = blockIdx.x * blockDim.x + threadIdx.x;
    float s = part[t] + part[BN + t];
    Z[t] = s;
    recC[2 * t] = pts4[t];
    recC[2 * t + 1] = make_float4(qv[t], radius[t], __logf(s), 0.f);
}

// ---------------- P4: colsum partials (LDS-staged col pass) ---------------
__global__ __launch_bounds__(1024, 8)
void p4_colsum(const float4* __restrict__ recC, const float4* __restrict__ recB,
               float* __restrict__ part) {
    __shared__ float4 stg[1024];
    __shared__ float s_red[16][64];
    int tid = threadIdx.x;
    int wave = __builtin_amdgcn_readfirstlane(tid >> 6);
    int lane = tid & 63;
    int g = blockIdx.x >> 1, half = blockIdx.x & 1;
    int b = g >> 6;
    const float4* src = recC + ((size_t)b * NN + (size_t)half * HALF) * 2;
    int col = g * 64 + lane;
    float4 fcc = recB[2 * col];
    float km = recB[2 * col + 1].x;
    float acc = 0.f;
    float4 pre = src[tid];
    for (int c = 0; c < 4; ++c) {
        __syncthreads();
        stg[tid] = pre;
        __syncthreads();
        if (c < 3) pre = src[(c + 1) * 1024 + tid];
        int j0 = wave * 32;
        #pragma unroll 8
        for (int j = j0; j < j0 + 32; ++j) {
            float4 fr = stg[2 * j];
            float4 an = stg[2 * j + 1];    // {q_n, rad_n, lnZ_n, 0}
            float dot = fr.x * fcc.x + fr.y * fcc.y + fr.z * fcc.z;
            float d = fmaf(-2.0f, dot, fr.w) + fcc.w;
            float e = __expf(an.x * km - an.z);
            acc += (d < an.y) ? e : 0.f;
        }
    }
    s_red[wave][lane] = acc;
    __syncthreads();
    if (tid < 64) {
        float s = 0.f;
        #pragma unroll
        for (int w = 0; w < 16; ++w) s += s_red[w][tid];
        part[half * BN + g * 64 + tid] = s;
    }
}

// ---------------- R4: colsum; recD = {pts4},{k, ln colsum, 0, 0} ----------
__global__ void r4_colsum(const float* __restrict__ part, const float4* __restrict__ pts4,
                          const float* __restrict__ kv, float* __restrict__ colsum,
                          float4* __restrict__ recD) {
    int t = blockIdx.x * blockDim.x + threadIdx.x;
    float s = fmaxf(part[t] + part[BN + t], 1e-12f);
    colsum[t] = s;
    recD[2 * t] = pts4[t];
    recD[2 * t + 1] = make_float4(kv[t], __logf(s), 0.f, 0.f);
}

// ---------------- P5: rs partials (LDS-staged row pass) -------------------
__global__ __launch_bounds__(1024, 8)
void p5_rs(const float4* __restrict__ recD, const float4* __restrict__ recB,
           float* __restrict__ part) {
    __shared__ float4 stg[1024];
    __shared__ float s_red[16][64];
    int tid = threadIdx.x;
    int wave = __builtin_amdgcn_readfirstlane(tid >> 6);
    int lane = tid & 63;
    int g = blockIdx.x >> 1, half = blockIdx.x & 1;
    int b = g >> 6;
    const float4* src = recD + ((size_t)b * NN + (size_t)half * HALF) * 2;
    int row = g * 64 + lane;
    float4 fr = recB[2 * row];
    float4 rowa = recB[2 * row + 1];
    float qn = rowa.y, rad = rowa.z;
    float acc = 0.f;
    float4 pre = src[tid];
    for (int c = 0; c < 4; ++c) {
        __syncthreads();
        stg[tid] = pre;
        __syncthreads();
        if (c < 3) pre = src[(c + 1) * 1024 + tid];
        int j0 = wave * 32;
        #pragma unroll 8
        for (int j = j0; j < j0 + 32; ++j) {
            float4 fc = stg[2 * j];
            float4 an = stg[2 * j + 1];    // {k_m, ln colsum_m, 0, 0}
            float dot = fr.x * fc.x + fr.y * fc.y + fr.z * fc.z;
            float d = fmaf(-2.0f, dot, fr.w) + fc.w;
            float e = __expf(qn * an.x - an.y);
            acc += (d < rad) ? e : 0.f;
        }
    }
    s_red[wave][lane] = acc;
    __syncthreads();
    if (tid < 64) {
        float s = 0.f;
        #pragma unroll
        for (int w = 0; w < 16; ++w) s += s_red[w][tid];
        part[half * BN + g * 64 + tid] = s;
    }
}

// ---------------- R5: rs; recE = {pts4},{q, rad, lnZ + ln rs, 0} ----------
__global__ void r5_rs(const float* __restrict__ part, const float* __restrict__ Z,
                      const float4* __restrict__ recC, const float4* __restrict__ pts4,
                      float4* __restrict__ recE) {
    int t = blockIdx.x * blockDim.x + threadIdx.x;
    float s = part[t] + part[BN + t];
    float rs = fmaxf(s / Z[t], 1e-12f);
    float4 a = recC[2 * t + 1];          // {q, rad, lnZ, 0}
    recE[2 * t] = pts4[t];
    recE[2 * t + 1] = make_float4(a.x, a.y, a.z + __logf(rs), 0.f);
}

// ---------------- P6: smoothed partials (LDS-staged col pass, 3 accs) -----
__global__ __launch_bounds__(1024, 8)
void p6_smooth(const float4* __restrict__ recE, const float4* __restrict__ recB,
               float* __restrict__ partx, float* __restrict__ party,
               float* __restrict__ partz) {
    __shared__ float4 stg[1024];
    __shared__ float s_rx[16][64];
    __shared__ float s_ry[16][64];
    __shared__ float s_rz[16][64];
    int tid = threadIdx.x;
    int wave = __builtin_amdgcn_readfirstlane(tid >> 6);
    int lane = tid & 63;
    int g = blockIdx.x >> 1, half = blockIdx.x & 1;
    int b = g >> 6;
    const float4* src = recE + ((size_t)b * NN + (size_t)half * HALF) * 2;
    int col = g * 64 + lane;
    float4 fcc = recB[2 * col];
    float km = recB[2 * col + 1].x;
    float ax = 0.f, ay = 0.f, az = 0.f;
    float4 pre = src[tid];
    for (int c = 0; c < 4; ++c) {
        __syncthreads();
        stg[tid] = pre;
        __syncthreads();
        if (c < 3) pre = src[(c + 1) * 1024 + tid];
        int j0 = wave * 32;
        #pragma unroll 8
        for (int j = j0; j < j0 + 32; ++j) {
            float4 fr = stg[2 * j];
            float4 an = stg[2 * j + 1];    // {q_n, rad_n, lnZ+ln rs, 0}
            float dot = fr.x * fcc.x + fr.y * fcc.y + fr.z * fcc.z;
            float d = fmaf(-2.0f, dot, fr.w) + fcc.w;
            float w = __expf(an.x * km - an.z);
            w = (d < an.y) ? w : 0.f;
            ax += fr.x * w;
            ay += fr.y * w;
            az += fr.z * w;
        }
    }
    s_rx[wave][lane] = ax;
    s_ry[wave][lane] = ay;
    s_rz[wave][lane] = az;
    __syncthreads();
    if (tid < 64) {
        float sx = 0.f, sy = 0.f, sz = 0.f;
        #pragma unroll
        for (int w = 0; w < 16; ++w) {
            sx += s_rx[w][tid];
            sy += s_ry[w][tid];
            sz += s_rz[w][tid];
        }
        int o = half * BN + g * 64 + tid;
        partx[o] = sx;
        party[o] = sy;
        partz[o] = sz;
    }
}

// ---------------- K8: fused epilogue (+ smoothed reduce), 8 thr/point -----
__global__ void k8_final(const float* __restrict__ xyz,
                         const float* __restrict__ partx, const float* __restrict__ party,
                         const float* __restrict__ partz, const float* __restrict__ colsum,
                         const int* __restrict__ idxg,
                         const float* __restrict__ w_v, const float* __restrict__ g_v, const float* __restrict__ b_v,
                         const float* __restrict__ w_pe, const float* __restrict__ b_pe,
                         const float* __restrict__ g_pe, const float* __restrict__ bb_pe,
                         const float* __restrict__ w_m1, const float* __restrict__ g_m1, const float* __restrict__ b_m1,
                         const float* __restrict__ w_m2, const float* __restrict__ g_m2, const float* __restrict__ b_m2,
                         const float* __restrict__ w_out, const float* __restrict__ g_out, const float* __restrict__ b_out,
                         float* __restrict__ out) {
    __shared__ float s_pf8[32][9];
    __shared__ float s_pf16[32][17];
    __shared__ float s_g64[32][65];
    int tid = threadIdx.x;
    int ptL = tid >> 3, o = tid & 7;
    int p = blockIdx.x * 32 + ptL;
    int b = p / NN, n = p % NN;
    const float* xb = xyz + (size_t)b * 3 * NN;
    float x = xb[n], y = xb[NN + n], z = xb[2 * NN + n];
    const float invs = rsqrtf(1.0f + 1e-5f);

    // phase A: PE 9->8, gelu(bn), max over K; thread = channel o
    float w0 = w_pe[o * 9 + 0], w1 = w_pe[o * 9 + 1], w2 = w_pe[o * 9 + 2];
    float w3 = w_pe[o * 9 + 3], w4 = w_pe[o * 9 + 4], w5 = w_pe[o * 9 + 5];
    float w6 = w_pe[o * 9 + 6], w7 = w_pe[o * 9 + 7], w8 = w_pe[o * 9 + 8];
    float bp = b_pe[o], gp = g_pe[o] * invs, bbp = bb_pe[o];
    float mx = -1e30f;
    for (int kk = 0; kk < KNBR; ++kk) {
        int j = idxg[(size_t)p * KNBR + kk];
        float gx = xb[j], gy = xb[NN + j], gz = xb[2 * NN + j];
        float dx = gx - x, dy = gy - y, dz = gz - z;
        float s = w0 * x + w1 * y + w2 * z + w3 * gx + w4 * gy + w5 * gz
                + w6 * dx + w7 * dy + w8 * dz + bp;
        s = gelu_f(s * gp + bbp);
        mx = fmaxf(mx, s);
    }
    s_pf8[ptL][o] = mx;
    __syncthreads();

    // phase B: m1 8->16, outputs o and o+8
    #pragma unroll
    for (int rr = 0; rr < 2; ++rr) {
        int r = o + rr * 8;
        const float* w = w_m1 + r * 8;
        float s = 0.f;
        #pragma unroll
        for (int c = 0; c < 8; ++c) s += w[c] * s_pf8[ptL][c];
        s_pf16[ptL][r] = gelu_f(s * (g_m1[r] * invs) + b_m1[r]);
    }
    __syncthreads();

    // phase C: m2 16->64 + value conv, gelu(v+pos); channels o*8..o*8+7
    float inv = 1.0f / colsum[p];
    float vx = (partx[p] + partx[BN + p]) * inv - x;
    float vy = (party[p] + party[BN + p]) * inv - y;
    float vz = (partz[p] + partz[BN + p]) * inv - z;
    #pragma unroll
    for (int i = 0; i < 8; ++i) {
        int ch = o * 8 + i;
        const float* wm = w_m2 + ch * 16;
        float pos = 0.f;
        #pragma unroll
        for (int c = 0; c < 16; ++c) pos += wm[c] * s_pf16[ptL][c];
        pos = pos * (g_m2[ch] * invs) + b_m2[ch];
        const float* wv = w_v + ch * 6;
        float vv = wv[0] * vx + wv[1] * vy + wv[2] * vz + wv[3] * x + wv[4] * y + wv[5] * z;
        vv = vv * (g_v[ch] * invs) + b_v[ch];
        s_g64[ptL][ch] = gelu_f(vv + pos);
    }
    __syncthreads();

    // phase D: out conv 64->32 + BN; outputs o*4..o*4+3
    #pragma unroll
    for (int i = 0; i < 4; ++i) {
        int ch = o * 4 + i;
        const float* w = w_out + ch * 64;
        float s = 0.f;
        #pragma unroll
        for (int c = 0; c < 64; ++c) s += w[c] * s_g64[ptL][c];
        out[((size_t)b * 32 + ch) * NN + n] = s * (g_out[ch] * invs) + b_out[ch];
    }
}

extern "C" void kernel_launch(void* const* d_in, const int* in_sizes, int n_in,
                              void* d_out, int out_size, void* d_ws, size_t ws_size,
                              hipStream_t stream) {
    const float* xyz  = (const float*)d_in[0];
    const float* w_q  = (const float*)d_in[1];
    const float* g_q  = (const float*)d_in[2];
    const float* b_q  = (const float*)d_in[3];
    const float* w_k  = (const float*)d_in[4];
    const float* g_k  = (const float*)d_in[5];
    const float* b_k  = (const float*)d_in[6];
    const float* w_v  = (const float*)d_in[7];
    const float* g_v  = (const float*)d_in[8];
    const float* b_v  = (const float*)d_in[9];
    const float* w_pe = (const float*)d_in[10];
    const float* b_pe = (const float*)d_in[11];
    const float* g_pe = (const float*)d_in[12];
    const float* bb_pe= (const float*)d_in[13];
    const float* w_m1 = (const float*)d_in[14];
    const float* g_m1 = (const float*)d_in[15];
    const float* b_m1 = (const float*)d_in[16];
    const float* w_m2 = (const float*)d_in[17];
    const float* g_m2 = (const float*)d_in[18];
    const float* b_m2 = (const float*)d_in[19];
    const float* w_out= (const float*)d_in[20];
    const float* g_out= (const float*)d_in[21];
    const float* b_out= (const float*)d_in[22];

    float* ws = (float*)d_ws;
    float*  qv     = ws;                               // BN
    float*  kv     = ws + (size_t)1  * BN;             // BN
    float4* pts4   = (float4*)(ws + (size_t)2  * BN);  // 4BN
    float*  radius = ws + (size_t)6  * BN;             // BN
    float*  Zv     = ws + (size_t)7  * BN;             // BN
    float*  colsum = ws + (size_t)8  * BN;             // BN
    float4* recB   = (float4*)(ws + (size_t)9  * BN);  // 8BN
    float4* recC   = (float4*)(ws + (size_t)17 * BN);  // 8BN
    float4* recD   = (float4*)(ws + (size_t)25 * BN);  // 8BN
    float4* recE   = (float4*)(ws + (size_t)33 * BN);  // 8BN
    int*    idxg   = (int*)   (ws + (size_t)41 * BN);  // 20BN
    float*  part1  = ws + (size_t)61 * BN;             // 2BN
    float*  part3  = ws + (size_t)63 * BN;             // 2BN
    float*  part5  = ws + (size_t)65 * BN;             // 2BN
    float*  part7  = ws + (size_t)67 * BN;             // 2BN
    float*  partx  = ws + (size_t)69 * BN;             // 2BN
    float*  party  = ws + (size_t)71 * BN;             // 2BN
    float*  partz  = ws + (size_t)73 * BN;             // 2BN

    const int PB = (BN / 64) * 2;   // 512 blocks of 1024 threads

    k0_prep<<<BN / 256, 256, 0, stream>>>(xyz, w_q, g_q, b_q, w_k, g_k, b_k, qv, kv, pts4);
    p1_kd<<<PB, 1024, 0, stream>>>(pts4, part1);
    k2_radius<<<BB, 1024, 0, stream>>>(part1, pts4, qv, kv, radius, recB);
    p3_Zk7<<<PB, 1024, 0, stream>>>(recB, pts4, radius, part3, idxg);
    r3_Z<<<BN / 256, 256, 0, stream>>>(part3, pts4, qv, radius, Zv, recC);
    p4_colsum<<<PB, 1024, 0, stream>>>(recC, recB, part5);
    r4_colsum<<<BN / 256, 256, 0, stream>>>(part5, pts4, kv, colsum, recD);
    p5_rs<<<PB, 1024, 0, stream>>>(recD, recB, part7);
    r5_rs<<<BN / 256, 256, 0, stream>>>(part7, Zv, recC, pts4, recE);
    p6_smooth<<<PB, 1024, 0, stream>>>(recE, recB, partx, party, partz);
    k8_final<<<BN / 32, 256, 0, stream>>>(xyz, partx, party, partz, colsum, idxg,
                                          w_v, g_v, b_v,
                                          w_pe, b_pe, g_pe, bb_pe,
                                          w_m1, g_m1, b_m1,
                                          w_m2, g_m2, b_m2,
                                          w_out, g_out, b_out,
                                          (float*)d_out);
}

// Round 7
// 251.570 us; speedup vs baseline: 1.1519x; 1.1519x over previous
//
#include <hip/hip_runtime.h>
#include <math.h>

#define BB 4
#define NN 4096
#define KNBR 20
#define BN (BB * NN)
#define NSLICE 8
#define SLEN (NN / NSLICE)     // 512 summed indices per slice
#define JPW (SLEN / 16)        // 32 summed indices per wave

__device__ __forceinline__ float gelu_f(float x) {
    return 0.5f * x * (1.0f + erff(x * 0.70710678118654752440f));
}

// ---------------- K0: per-point precompute: q, k, packed (x,y,z,|p|^2) ----
__global__ void k0_prep(const float* __restrict__ xyz,
                        const float* __restrict__ w_q, const float* __restrict__ g_q, const float* __restrict__ b_q,
                        const float* __restrict__ w_k, const float* __restrict__ g_k, const float* __restrict__ b_k,
                        float* __restrict__ qv, float* __restrict__ kv, float4* __restrict__ pts4) {
    int t = blockIdx.x * blockDim.x + threadIdx.x;
    if (t >= BN) return;
    int b = t / NN, n = t % NN;
    const float* base = xyz + (size_t)b * 3 * NN;
    float x = base[n], y = base[NN + n], z = base[2 * NN + n];
    float sq = x * x + y * y + z * z;
    const float invs = rsqrtf(1.0f + 1e-5f);
    float qr = x * (w_q[0] + w_q[3]) + y * (w_q[1] + w_q[4]) + z * (w_q[2] + w_q[5]);
    float kr = x * (w_k[0] + w_k[3]) + y * (w_k[1] + w_k[4]) + z * (w_k[2] + w_k[5]);
    qv[t] = qr * (g_q[0] * invs) + b_q[0];
    kv[t] = kr * (g_k[0] * invs) + b_k[0];
    pts4[t] = make_float4(x, y, z, sq);
}

// Pass decomposition: grid = 64 output-groups (256 pts) x 8 sum-slices (512).
// Block 1024 thr = 16 waves; wave w handles summed indices [w*32, w*32+32).
// Lane handles 4 output rows: g*256 + rr*64 + lane. Uniform summed loads.

// ---------------- P1: kd partials ----------------------------------------
__global__ __launch_bounds__(1024, 8)
void p1_kd(const float4* __restrict__ pts4, float* __restrict__ part) {
    __shared__ float s_red[16][256];
    int tid = threadIdx.x;
    int wave = __builtin_amdgcn_readfirstlane(tid >> 6);
    int lane = tid & 63;
    int g = blockIdx.x >> 3, slice = blockIdx.x & 7;
    int b = g >> 4;
    const float4* rb = pts4 + (size_t)b * NN + slice * SLEN + wave * JPW;
    float4 fr[4];
    float acc[4] = {0.f, 0.f, 0.f, 0.f};
    #pragma unroll
    for (int rr = 0; rr < 4; ++rr) fr[rr] = pts4[g * 256 + rr * 64 + lane];
    #pragma unroll 4
    for (int j = 0; j < JPW; ++j) {
        float4 fc = rb[j];
        #pragma unroll
        for (int rr = 0; rr < 4; ++rr) {
            float dot = fr[rr].x * fc.x + fr[rr].y * fc.y + fr[rr].z * fc.z;
            float d = fmaf(-2.0f, dot, fr[rr].w) + fc.w;
            acc[rr] += __expf(-50.0f * d);
        }
    }
    #pragma unroll
    for (int rr = 0; rr < 4; ++rr) s_red[wave][rr * 64 + lane] = acc[rr];
    __syncthreads();
    if (tid < 256) {
        float s = 0.f;
        #pragma unroll
        for (int w = 0; w < 16; ++w) s += s_red[w][tid];
        part[slice * BN + g * 256 + tid] = s;
    }
}

// ---------------- K2: reduce kd + per-batch max -> radius; write recB -----
// recB[2n] = {x,y,z,sq}; recB[2n+1] = {k, q, rad, 0}
__global__ void k2_radius(const float* __restrict__ part, const float4* __restrict__ pts4,
                          const float* __restrict__ qv, const float* __restrict__ kv,
                          float* __restrict__ radius, float4* __restrict__ recB) {
    int b = blockIdx.x;
    int t = threadIdx.x;   // 1024
    float kdv[4];
    float mx = -1e30f;
    #pragma unroll
    for (int j = 0; j < 4; ++j) {
        int n = b * NN + j * 1024 + t;
        float s = 0.f;
        #pragma unroll
        for (int c = 0; c < NSLICE; ++c) s += part[c * BN + n];
        kdv[j] = s;
        mx = fmaxf(mx, s);
    }
    __shared__ float red[1024];
    red[t] = mx;
    __syncthreads();
    for (int s = 512; s > 0; s >>= 1) {
        if (t < s) red[t] = fmaxf(red[t], red[t + s]);
        __syncthreads();
    }
    float kmax = red[0];
    #pragma unroll
    for (int j = 0; j < 4; ++j) {
        int n = b * NN + j * 1024 + t;
        float rad = 0.1f + 0.1f * (kdv[j] / (kmax + 1e-9f));
        radius[n] = rad;
        recB[2 * n] = pts4[n];
        recB[2 * n + 1] = make_float4(kv[n], qv[n], rad, 0.f);
    }
}

// ---------------- P3: Z partials + k7 neighbor scan ----------------------
__global__ __launch_bounds__(1024, 8)
void p3_Zk7(const float4* __restrict__ recB, const float4* __restrict__ pts4,
            const float* __restrict__ radius, float* __restrict__ part,
            int* __restrict__ idxg) {
    __shared__ float s_red[16][256];
    int tid = threadIdx.x;
    int wave = __builtin_amdgcn_readfirstlane(tid >> 6);
    int lane = tid & 63;
    int g = blockIdx.x >> 3, slice = blockIdx.x & 7;
    int b = g >> 4;
    const float4* rb = recB + ((size_t)b * NN + slice * SLEN + wave * JPW) * 2;
    float4 fr[4];
    float q[4], rad[4];
    float acc[4] = {0.f, 0.f, 0.f, 0.f};
    #pragma unroll
    for (int rr = 0; rr < 4; ++rr) {
        int r = g * 256 + rr * 64 + lane;
        fr[rr] = recB[2 * r];
        float4 a = recB[2 * r + 1];
        q[rr] = a.y;
        rad[rr] = a.z;
    }
    #pragma unroll 4
    for (int j = 0; j < JPW; ++j) {
        float4 fc = rb[2 * j];
        float4 an = rb[2 * j + 1];          // {k, q, rad, 0}
        #pragma unroll
        for (int rr = 0; rr < 4; ++rr) {
            float dot = fr[rr].x * fc.x + fr[rr].y * fc.y + fr[rr].z * fc.z;
            float d = fmaf(-2.0f, dot, fr[rr].w) + fc.w;
            float e = __expf(q[rr] * an.x);
            acc[rr] += (d < rad[rr]) ? e : 0.f;
        }
    }
    #pragma unroll
    for (int rr = 0; rr < 4; ++rr) s_red[wave][rr * 64 + lane] = acc[rr];
    __syncthreads();
    if (tid < 256) {
        float s = 0.f;
        #pragma unroll
        for (int w = 0; w < 16; ++w) s += s_red[w][tid];
        part[slice * BN + g * 256 + tid] = s;
    }
    // k7: first-20-by-index in-ball neighbors; 2 rows per wave
    int gw = blockIdx.x * 16 + wave;
    for (int rr = 0; rr < 2; ++rr) {
        int row7 = gw * 2 + rr;
        int b7 = row7 / NN;
        const float4* p7 = pts4 + (size_t)b7 * NN;
        float4 f7 = pts4[row7];
        float rad7 = radius[row7];
        int total = 0, firstm = 0;
        bool have = false;
        unsigned long long lmask = (1ULL << lane) - 1ULL;
        for (int i = 0; i < NN / 64 && total < KNBR; ++i) {
            int m = i * 64 + lane;
            float4 fc = p7[m];
            float dot = f7.x * fc.x + f7.y * fc.y + f7.z * fc.z;
            float d = fmaf(-2.0f, dot, f7.w) + fc.w;
            bool inb = !(d > rad7);   // dist <= radius
            unsigned long long mask = __ballot(inb);
            if (!have && mask != 0ULL) {
                int src7 = __ffsll(mask) - 1;
                firstm = __shfl(m, src7);
                have = true;
            }
            int pos = total + (int)__popcll(mask & lmask);
            if (inb && pos < KNBR) idxg[(size_t)row7 * KNBR + pos] = m;
            total += (int)__popcll(mask);
        }
        if (total < KNBR && lane >= total && lane < KNBR)
            idxg[(size_t)row7 * KNBR + lane] = firstm;
    }
}

// ---------------- R3: Z = sum; recC = {pts4},{q, rad, lnZ, 0} -------------
__global__ void r3_Z(const float* __restrict__ part, const float4* __restrict__ pts4,
                     const float* __restrict__ qv, const float* __restrict__ radius,
                     float* __restrict__ Z, float4* __restrict__ recC) {
    int t = blockIdx.x * blockDim.x + threadIdx.x;
    float s = 0.f;
    #pragma unroll
    for (int c = 0; c < NSLICE; ++c) s += part[c * BN + t];
    Z[t] = s;
    recC[2 * t] = pts4[t];
    recC[2 * t + 1] = make_float4(qv[t], radius[t], __logf(s), 0.f);
}

// ---------------- P4: colsum partials (col pass) --------------------------
__global__ __launch_bounds__(1024, 8)
void p4_colsum(const float4* __restrict__ recC, const float4* __restrict__ recB,
               float* __restrict__ part) {
    __shared__ float s_red[16][256];
    int tid = threadIdx.x;
    int wave = __builtin_amdgcn_readfirstlane(tid >> 6);
    int lane = tid & 63;
    int g = blockIdx.x >> 3, slice = blockIdx.x & 7;
    int b = g >> 4;
    const float4* rb = recC + ((size_t)b * NN + slice * SLEN + wave * JPW) * 2;
    float4 fcc[4];
    float km[4];
    float acc[4] = {0.f, 0.f, 0.f, 0.f};
    #pragma unroll
    for (int rr = 0; rr < 4; ++rr) {
        int c = g * 256 + rr * 64 + lane;
        fcc[rr] = recB[2 * c];
        km[rr] = recB[2 * c + 1].x;
    }
    #pragma unroll 4
    for (int j = 0; j < JPW; ++j) {
        float4 fc = rb[2 * j];              // row point n
        float4 an = rb[2 * j + 1];          // {q_n, rad_n, lnZ_n, 0}
        #pragma unroll
        for (int rr = 0; rr < 4; ++rr) {
            float dot = fc.x * fcc[rr].x + fc.y * fcc[rr].y + fc.z * fcc[rr].z;
            float d = fmaf(-2.0f, dot, fc.w) + fcc[rr].w;
            float e = __expf(an.x * km[rr] - an.z);
            acc[rr] += (d < an.y) ? e : 0.f;
        }
    }
    #pragma unroll
    for (int rr = 0; rr < 4; ++rr) s_red[wave][rr * 64 + lane] = acc[rr];
    __syncthreads();
    if (tid < 256) {
        float s = 0.f;
        #pragma unroll
        for (int w = 0; w < 16; ++w) s += s_red[w][tid];
        part[slice * BN + g * 256 + tid] = s;
    }
}

// ---------------- R4: colsum; recD = {pts4},{k, ln colsum, 0, 0} ----------
__global__ void r4_colsum(const float* __restrict__ part, const float4* __restrict__ pts4,
                          const float* __restrict__ kv, float* __restrict__ colsum,
                          float4* __restrict__ recD) {
    int t = blockIdx.x * blockDim.x + threadIdx.x;
    float s = 0.f;
    #pragma unroll
    for (int c = 0; c < NSLICE; ++c) s += part[c * BN + t];
    s = fmaxf(s, 1e-12f);
    colsum[t] = s;
    recD[2 * t] = pts4[t];
    recD[2 * t + 1] = make_float4(kv[t], __logf(s), 0.f, 0.f);
}

// ---------------- P5: rs partials (row pass) ------------------------------
__global__ __launch_bounds__(1024, 8)
void p5_rs(const float4* __restrict__ recD, const float4* __restrict__ recB,
           float* __restrict__ part) {
    __shared__ float s_red[16][256];
    int tid = threadIdx.x;
    int wave = __builtin_amdgcn_readfirstlane(tid >> 6);
    int lane = tid & 63;
    int g = blockIdx.x >> 3, slice = blockIdx.x & 7;
    int b = g >> 4;
    const float4* rb = recD + ((size_t)b * NN + slice * SLEN + wave * JPW) * 2;
    float4 fr[4];
    float q[4], rad[4];
    float acc[4] = {0.f, 0.f, 0.f, 0.f};
    #pragma unroll
    for (int rr = 0; rr < 4; ++rr) {
        int r = g * 256 + rr * 64 + lane;
        fr[rr] = recB[2 * r];
        float4 a = recB[2 * r + 1];
        q[rr] = a.y;
        rad[rr] = a.z;
    }
    #pragma unroll 4
    for (int j = 0; j < JPW; ++j) {
        float4 fc = rb[2 * j];
        float4 an = rb[2 * j + 1];          // {k_m, ln colsum_m, 0, 0}
        #pragma unroll
        for (int rr = 0; rr < 4; ++rr) {
            float dot = fr[rr].x * fc.x + fr[rr].y * fc.y + fr[rr].z * fc.z;
            float d = fmaf(-2.0f, dot, fr[rr].w) + fc.w;
            float e = __expf(q[rr] * an.x - an.y);
            acc[rr] += (d < rad[rr]) ? e : 0.f;
        }
    }
    #pragma unroll
    for (int rr = 0; rr < 4; ++rr) s_red[wave][rr * 64 + lane] = acc[rr];
    __syncthreads();
    if (tid < 256) {
        float s = 0.f;
        #pragma unroll
        for (int w = 0; w < 16; ++w) s += s_red[w][tid];
        part[slice * BN + g * 256 + tid] = s;
    }
}

// ---------------- R5: rs; recE = {pts4},{q, rad, lnZ + ln rs, 0} ----------
__global__ void r5_rs(const float* __restrict__ part, const float* __restrict__ Z,
                      const float4* __restrict__ recC, const float4* __restrict__ pts4,
                      float4* __restrict__ recE) {
    int t = blockIdx.x * blockDim.x + threadIdx.x;
    float s = 0.f;
    #pragma unroll
    for (int c = 0; c < NSLICE; ++c) s += part[c * BN + t];
    float rs = fmaxf(s / Z[t], 1e-12f);
    float4 a = recC[2 * t + 1];          // {q, rad, lnZ, 0}
    recE[2 * t] = pts4[t];
    recE[2 * t + 1] = make_float4(a.x, a.y, a.z + __logf(rs), 0.f);
}

// ---------------- P6: smoothed partials (col pass, 3 accumulators) --------
__global__ __launch_bounds__(1024, 8)
void p6_smooth(const float4* __restrict__ recE, const float4* __restrict__ recB,
               float* __restrict__ partx, float* __restrict__ party,
               float* __restrict__ partz) {
    __shared__ float s_rx[16][256];
    __shared__ float s_ry[16][256];
    __shared__ float s_rz[16][256];
    int tid = threadIdx.x;
    int wave = __builtin_amdgcn_readfirstlane(tid >> 6);
    int lane = tid & 63;
    int g = blockIdx.x >> 3, slice = blockIdx.x & 7;
    int b = g >> 4;
    const float4* rb = recE + ((size_t)b * NN + slice * SLEN + wave * JPW) * 2;
    float4 fcc[4];
    float km[4];
    float ax[4] = {0.f, 0.f, 0.f, 0.f};
    float ay[4] = {0.f, 0.f, 0.f, 0.f};
    float az[4] = {0.f, 0.f, 0.f, 0.f};
    #pragma unroll
    for (int rr = 0; rr < 4; ++rr) {
        int c = g * 256 + rr * 64 + lane;
        fcc[rr] = recB[2 * c];
        km[rr] = recB[2 * c + 1].x;
    }
    #pragma unroll 2
    for (int j = 0; j < JPW; ++j) {
        float4 fc = rb[2 * j];              // row point n
        float4 an = rb[2 * j + 1];          // {q_n, rad_n, lnZ+ln rs, 0}
        #pragma unroll
        for (int rr = 0; rr < 4; ++rr) {
            float dot = fc.x * fcc[rr].x + fc.y * fcc[rr].y + fc.z * fcc[rr].z;
            float d = fmaf(-2.0f, dot, fc.w) + fcc[rr].w;
            float w = __expf(an.x * km[rr] - an.z);
            w = (d < an.y) ? w : 0.f;
            ax[rr] += fc.x * w;
            ay[rr] += fc.y * w;
            az[rr] += fc.z * w;
        }
    }
    #pragma unroll
    for (int rr = 0; rr < 4; ++rr) {
        s_rx[wave][rr * 64 + lane] = ax[rr];
        s_ry[wave][rr * 64 + lane] = ay[rr];
        s_rz[wave][rr * 64 + lane] = az[rr];
    }
    __syncthreads();
    if (tid < 256) {
        float sx = 0.f, sy = 0.f, sz = 0.f;
        #pragma unroll
        for (int w = 0; w < 16; ++w) {
            sx += s_rx[w][tid];
            sy += s_ry[w][tid];
            sz += s_rz[w][tid];
        }
        int o = slice * BN + g * 256 + tid;
        partx[o] = sx;
        party[o] = sy;
        partz[o] = sz;
    }
}

// ---------------- K8: fused epilogue (+ smoothed reduce), 8 thr/point -----
__global__ void k8_final(const float* __restrict__ xyz,
                         const float* __restrict__ partx, const float* __restrict__ party,
                         const float* __restrict__ partz, const float* __restrict__ colsum,
                         const int* __restrict__ idxg,
                         const float* __restrict__ w_v, const float* __restrict__ g_v, const float* __restrict__ b_v,
                         const float* __restrict__ w_pe, const float* __restrict__ b_pe,
                         const float* __restrict__ g_pe, const float* __restrict__ bb_pe,
                         const float* __restrict__ w_m1, const float* __restrict__ g_m1, const float* __restrict__ b_m1,
                         const float* __restrict__ w_m2, const float* __restrict__ g_m2, const float* __restrict__ b_m2,
                         const float* __restrict__ w_out, const float* __restrict__ g_out, const float* __restrict__ b_out,
                         float* __restrict__ out) {
    __shared__ float s_pf8[32][9];
    __shared__ float s_pf16[32][17];
    __shared__ float s_g64[32][65];
    int tid = threadIdx.x;
    int ptL = tid >> 3, o = tid & 7;
    int p = blockIdx.x * 32 + ptL;
    int b = p / NN, n = p % NN;
    const float* xb = xyz + (size_t)b * 3 * NN;
    float x = xb[n], y = xb[NN + n], z = xb[2 * NN + n];
    const float invs = rsqrtf(1.0f + 1e-5f);

    // phase A: PE 9->8, gelu(bn), max over K; thread = channel o
    float w0 = w_pe[o * 9 + 0], w1 = w_pe[o * 9 + 1], w2 = w_pe[o * 9 + 2];
    float w3 = w_pe[o * 9 + 3], w4 = w_pe[o * 9 + 4], w5 = w_pe[o * 9 + 5];
    float w6 = w_pe[o * 9 + 6], w7 = w_pe[o * 9 + 7], w8 = w_pe[o * 9 + 8];
    float bp = b_pe[o], gp = g_pe[o] * invs, bbp = bb_pe[o];
    float mx = -1e30f;
    for (int kk = 0; kk < KNBR; ++kk) {
        int j = idxg[(size_t)p * KNBR + kk];
        float gx = xb[j], gy = xb[NN + j], gz = xb[2 * NN + j];
        float dx = gx - x, dy = gy - y, dz = gz - z;
        float s = w0 * x + w1 * y + w2 * z + w3 * gx + w4 * gy + w5 * gz
                + w6 * dx + w7 * dy + w8 * dz + bp;
        s = gelu_f(s * gp + bbp);
        mx = fmaxf(mx, s);
    }
    s_pf8[ptL][o] = mx;
    __syncthreads();

    // phase B: m1 8->16, outputs o and o+8
    #pragma unroll
    for (int rr = 0; rr < 2; ++rr) {
        int r = o + rr * 8;
        const float* w = w_m1 + r * 8;
        float s = 0.f;
        #pragma unroll
        for (int c = 0; c < 8; ++c) s += w[c] * s_pf8[ptL][c];
        s_pf16[ptL][r] = gelu_f(s * (g_m1[r] * invs) + b_m1[r]);
    }
    __syncthreads();

    // phase C: m2 16->64 + value conv, gelu(v+pos); channels o*8..o*8+7
    float inv = 1.0f / colsum[p];
    float sx = 0.f, sy = 0.f, sz = 0.f;
    #pragma unroll
    for (int c = 0; c < NSLICE; ++c) {
        sx += partx[c * BN + p];
        sy += party[c * BN + p];
        sz += partz[c * BN + p];
    }
    float vx = sx * inv - x, vy = sy * inv - y, vz = sz * inv - z;
    #pragma unroll
    for (int i = 0; i < 8; ++i) {
        int ch = o * 8 + i;
        const float* wm = w_m2 + ch * 16;
        float pos = 0.f;
        #pragma unroll
        for (int c = 0; c < 16; ++c) pos += wm[c] * s_pf16[ptL][c];
        pos = pos * (g_m2[ch] * invs) + b_m2[ch];
        const float* wv = w_v + ch * 6;
        float vv = wv[0] * vx + wv[1] * vy + wv[2] * vz + wv[3] * x + wv[4] * y + wv[5] * z;
        vv = vv * (g_v[ch] * invs) + b_v[ch];
        s_g64[ptL][ch] = gelu_f(vv + pos);
    }
    __syncthreads();

    // phase D: out conv 64->32 + BN; outputs o*4..o*4+3
    #pragma unroll
    for (int i = 0; i < 4; ++i) {
        int ch = o * 4 + i;
        const float* w = w_out + ch * 64;
        float s = 0.f;
        #pragma unroll
        for (int c = 0; c < 64; ++c) s += w[c] * s_g64[ptL][c];
        out[((size_t)b * 32 + ch) * NN + n] = s * (g_out[ch] * invs) + b_out[ch];
    }
}

extern "C" void kernel_launch(void* const* d_in, const int* in_sizes, int n_in,
                              void* d_out, int out_size, void* d_ws, size_t ws_size,
                              hipStream_t stream) {
    const float* xyz  = (const float*)d_in[0];
    const float* w_q  = (const float*)d_in[1];
    const float* g_q  = (const float*)d_in[2];
    const float* b_q  = (const float*)d_in[3];
    const float* w_k  = (const float*)d_in[4];
    const float* g_k  = (const float*)d_in[5];
    const float* b_k  = (const float*)d_in[6];
    const float* w_v  = (const float*)d_in[7];
    const float* g_v  = (const float*)d_in[8];
    const float* b_v  = (const float*)d_in[9];
    const float* w_pe = (const float*)d_in[10];
    const float* b_pe = (const float*)d_in[11];
    const float* g_pe = (const float*)d_in[12];
    const float* bb_pe= (const float*)d_in[13];
    const float* w_m1 = (const float*)d_in[14];
    const float* g_m1 = (const float*)d_in[15];
    const float* b_m1 = (const float*)d_in[16];
    const float* w_m2 = (const float*)d_in[17];
    const float* g_m2 = (const float*)d_in[18];
    const float* b_m2 = (const float*)d_in[19];
    const float* w_out= (const float*)d_in[20];
    const float* g_out= (const float*)d_in[21];
    const float* b_out= (const float*)d_in[22];

    float* ws = (float*)d_ws;
    float*  qv     = ws;                               // BN
    float*  kv     = ws + (size_t)1  * BN;             // BN
    float4* pts4   = (float4*)(ws + (size_t)2  * BN);  // 4BN
    float*  radius = ws + (size_t)6  * BN;             // BN
    float*  Zv     = ws + (size_t)7  * BN;             // BN
    float*  colsum = ws + (size_t)8  * BN;             // BN
    float4* recB   = (float4*)(ws + (size_t)9  * BN);  // 8BN
    float4* recC   = (float4*)(ws + (size_t)17 * BN);  // 8BN
    float4* recD   = (float4*)(ws + (size_t)25 * BN);  // 8BN
    float4* recE   = (float4*)(ws + (size_t)33 * BN);  // 8BN
    int*    idxg   = (int*)   (ws + (size_t)41 * BN);  // 20BN
    float*  part1  = ws + (size_t)61 * BN;             // 8BN
    float*  part3  = ws + (size_t)69 * BN;             // 8BN
    float*  part5  = ws + (size_t)77 * BN;             // 8BN
    float*  part7  = ws + (size_t)85 * BN;             // 8BN
    float*  partx  = ws + (size_t)93 * BN;             // 8BN
    float*  party  = ws + (size_t)101 * BN;            // 8BN
    float*  partz  = ws + (size_t)109 * BN;            // 8BN

    const int PB = (BN / 256) * NSLICE;   // 512 blocks of 1024 threads

    k0_prep<<<BN / 256, 256, 0, stream>>>(xyz, w_q, g_q, b_q, w_k, g_k, b_k, qv, kv, pts4);
    p1_kd<<<PB, 1024, 0, stream>>>(pts4, part1);
    k2_radius<<<BB, 1024, 0, stream>>>(part1, pts4, qv, kv, radius, recB);
    p3_Zk7<<<PB, 1024, 0, stream>>>(recB, pts4, radius, part3, idxg);
    r3_Z<<<BN / 256, 256, 0, stream>>>(part3, pts4, qv, radius, Zv, recC);
    p4_colsum<<<PB, 1024, 0, stream>>>(recC, recB, part5);
    r4_colsum<<<BN / 256, 256, 0, stream>>>(part5, pts4, kv, colsum, recD);
    p5_rs<<<PB, 1024, 0, stream>>>(recD, recB, part7);
    r5_rs<<<BN / 256, 256, 0, stream>>>(part7, Zv, recC, pts4, recE);
    p6_smooth<<<PB, 1024, 0, stream>>>(recE, recB, partx, party, partz);
    k8_final<<<BN / 32, 256, 0, stream>>>(xyz, partx, party, partz, colsum, idxg,
                                          w_v, g_v, b_v,
                                          w_pe, b_pe, g_pe, bb_pe,
                                          w_m1, g_m1, b_m1,
                                          w_m2, g_m2, b_m2,
                                          w_out, g_out, b_out,
                                          (float*)d_out);
}

// Round 8
// 244.725 us; speedup vs baseline: 1.1841x; 1.0280x over previous
//
#include <hip/hip_runtime.h>
#include <math.h>

#define BB 4
#define NN 4096
#define KNBR 20
#define BN (BB * NN)
#define NSLICE 8
#define SLEN (NN / NSLICE)     // 512 summed indices per slice
#define JPW (SLEN / 16)        // 32 summed indices per wave

__device__ __forceinline__ float gelu_f(float x) {
    return 0.5f * x * (1.0f + erff(x * 0.70710678118654752440f));
}

// Canonical point record: identical instruction sequence everywhere.
__device__ __forceinline__ float4 mkrec(const float* __restrict__ xb, int n) {
    float x = xb[n], y = xb[NN + n], z = xb[2 * NN + n];
    float sq = fmaf(x, x, fmaf(y, y, z * z));
    return make_float4(x, y, z, sq);
}

// Pass decomposition: grid = 64 output-groups (256 pts) x 8 sum-slices (512).
// Block 1024 thr = 16 waves; wave w handles summed indices [w*32, w*32+32).
// Lane handles 4 output rows: g*256 + rr*64 + lane. Uniform summed loads.

// ---------------- P1: kd partials (records on the fly) --------------------
__global__ __launch_bounds__(1024, 8)
void p1_kd(const float* __restrict__ xyz, float* __restrict__ part) {
    __shared__ float s_red[16][256];
    int tid = threadIdx.x;
    int wave = __builtin_amdgcn_readfirstlane(tid >> 6);
    int lane = tid & 63;
    int g = blockIdx.x >> 3, slice = blockIdx.x & 7;
    int b = g >> 4;
    const float* xb = xyz + (size_t)b * 3 * NN;
    int nbase = (g & 15) * 256;            // local n of group start
    float4 fr[4];
    float acc[4] = {0.f, 0.f, 0.f, 0.f};
    #pragma unroll
    for (int rr = 0; rr < 4; ++rr) fr[rr] = mkrec(xb, nbase + rr * 64 + lane);
    int m0 = slice * SLEN + wave * JPW;
    #pragma unroll 4
    for (int j = 0; j < JPW; ++j) {
        float4 fc = mkrec(xb, m0 + j);
        #pragma unroll
        for (int rr = 0; rr < 4; ++rr) {
            float dot = fr[rr].x * fc.x + fr[rr].y * fc.y + fr[rr].z * fc.z;
            float d = fmaf(-2.0f, dot, fr[rr].w) + fc.w;
            acc[rr] += __expf(-50.0f * d);
        }
    }
    #pragma unroll
    for (int rr = 0; rr < 4; ++rr) s_red[wave][rr * 64 + lane] = acc[rr];
    __syncthreads();
    if (tid < 256) {
        float s = 0.f;
        #pragma unroll
        for (int w = 0; w < 16; ++w) s += s_red[w][tid];
        part[slice * BN + g * 256 + tid] = s;
    }
}

// ---------------- K2: reduce kd + per-batch max; build recB ---------------
// recB[2n] = {x,y,z,sq}; recB[2n+1] = {k, q, rad, 0}
__global__ void k2_radius(const float* __restrict__ part, const float* __restrict__ xyz,
                          const float* __restrict__ w_q, const float* __restrict__ g_q, const float* __restrict__ b_q,
                          const float* __restrict__ w_k, const float* __restrict__ g_k, const float* __restrict__ b_k,
                          float4* __restrict__ recB) {
    int b = blockIdx.x;
    int t = threadIdx.x;   // 1024
    const float* xb = xyz + (size_t)b * 3 * NN;
    const float invs = rsqrtf(1.0f + 1e-5f);
    float kdv[4];
    float mx = -1e30f;
    #pragma unroll
    for (int j = 0; j < 4; ++j) {
        int n = b * NN + j * 1024 + t;
        float s = 0.f;
        #pragma unroll
        for (int c = 0; c < NSLICE; ++c) s += part[c * BN + n];
        kdv[j] = s;
        mx = fmaxf(mx, s);
    }
    __shared__ float red[1024];
    red[t] = mx;
    __syncthreads();
    for (int s = 512; s > 0; s >>= 1) {
        if (t < s) red[t] = fmaxf(red[t], red[t + s]);
        __syncthreads();
    }
    float kmax = red[0];
    #pragma unroll
    for (int j = 0; j < 4; ++j) {
        int nl = j * 1024 + t;
        int n = b * NN + nl;
        float rad = 0.1f + 0.1f * (kdv[j] / (kmax + 1e-9f));
        float4 r = mkrec(xb, nl);
        float qr = r.x * (w_q[0] + w_q[3]) + r.y * (w_q[1] + w_q[4]) + r.z * (w_q[2] + w_q[5]);
        float kr = r.x * (w_k[0] + w_k[3]) + r.y * (w_k[1] + w_k[4]) + r.z * (w_k[2] + w_k[5]);
        float q = qr * (g_q[0] * invs) + b_q[0];
        float k = kr * (g_k[0] * invs) + b_k[0];
        recB[2 * n] = r;
        recB[2 * n + 1] = make_float4(k, q, rad, 0.f);
    }
}

// ---------------- P3: Z partials + k7 neighbor scan ----------------------
__global__ __launch_bounds__(1024, 8)
void p3_Zk7(const float4* __restrict__ recB, float* __restrict__ part,
            int* __restrict__ idxg) {
    __shared__ float s_red[16][256];
    int tid = threadIdx.x;
    int wave = __builtin_amdgcn_readfirstlane(tid >> 6);
    int lane = tid & 63;
    int g = blockIdx.x >> 3, slice = blockIdx.x & 7;
    int b = g >> 4;
    const float4* rb = recB + ((size_t)b * NN + slice * SLEN + wave * JPW) * 2;
    float4 fr[4];
    float q[4], rad[4];
    float acc[4] = {0.f, 0.f, 0.f, 0.f};
    #pragma unroll
    for (int rr = 0; rr < 4; ++rr) {
        int r = g * 256 + rr * 64 + lane;
        fr[rr] = recB[2 * r];
        float4 a = recB[2 * r + 1];
        q[rr] = a.y;
        rad[rr] = a.z;
    }
    #pragma unroll 4
    for (int j = 0; j < JPW; ++j) {
        float4 fc = rb[2 * j];
        float4 an = rb[2 * j + 1];          // {k, q, rad, 0}
        #pragma unroll
        for (int rr = 0; rr < 4; ++rr) {
            float dot = fr[rr].x * fc.x + fr[rr].y * fc.y + fr[rr].z * fc.z;
            float d = fmaf(-2.0f, dot, fr[rr].w) + fc.w;
            float e = __expf(q[rr] * an.x);
            acc[rr] += (d < rad[rr]) ? e : 0.f;
        }
    }
    #pragma unroll
    for (int rr = 0; rr < 4; ++rr) s_red[wave][rr * 64 + lane] = acc[rr];
    __syncthreads();
    if (tid < 256) {
        float s = 0.f;
        #pragma unroll
        for (int w = 0; w < 16; ++w) s += s_red[w][tid];
        part[slice * BN + g * 256 + tid] = s;
    }
    // k7: first-20-by-index in-ball neighbors; 2 rows per wave
    int gw = blockIdx.x * 16 + wave;
    for (int rr = 0; rr < 2; ++rr) {
        int row7 = gw * 2 + rr;
        int b7 = row7 / NN;
        const float4* p7 = recB + (size_t)b7 * NN * 2;
        float4 f7 = recB[2 * row7];
        float rad7 = recB[2 * row7 + 1].z;
        int total = 0, firstm = 0;
        bool have = false;
        unsigned long long lmask = (1ULL << lane) - 1ULL;
        for (int i = 0; i < NN / 64 && total < KNBR; ++i) {
            int m = i * 64 + lane;
            float4 fc = p7[2 * m];
            float dot = f7.x * fc.x + f7.y * fc.y + f7.z * fc.z;
            float d = fmaf(-2.0f, dot, f7.w) + fc.w;
            bool inb = !(d > rad7);   // dist <= radius
            unsigned long long mask = __ballot(inb);
            if (!have && mask != 0ULL) {
                int src7 = __ffsll(mask) - 1;
                firstm = __shfl(m, src7);
                have = true;
            }
            int pos = total + (int)__popcll(mask & lmask);
            if (inb && pos < KNBR) idxg[(size_t)row7 * KNBR + pos] = m;
            total += (int)__popcll(mask);
        }
        if (total < KNBR && lane >= total && lane < KNBR)
            idxg[(size_t)row7 * KNBR + lane] = firstm;
    }
}

// ---------------- P4: colsum partials (col pass; lnZ prologue) ------------
__global__ __launch_bounds__(1024, 8)
void p4_colsum(const float4* __restrict__ recB, const float* __restrict__ part3,
               float* __restrict__ part) {
    __shared__ float s_red[16][256];
    __shared__ float s_lnZ[SLEN];
    int tid = threadIdx.x;
    int wave = __builtin_amdgcn_readfirstlane(tid >> 6);
    int lane = tid & 63;
    int g = blockIdx.x >> 3, slice = blockIdx.x & 7;
    int b = g >> 4;
    if (tid < SLEN) {
        int gn = b * NN + slice * SLEN + tid;
        float s = 0.f;
        #pragma unroll
        for (int c = 0; c < NSLICE; ++c) s += part3[c * BN + gn];
        s_lnZ[tid] = __logf(s);
    }
    const float4* rb = recB + ((size_t)b * NN + slice * SLEN + wave * JPW) * 2;
    float4 fcc[4];
    float km[4];
    float acc[4] = {0.f, 0.f, 0.f, 0.f};
    #pragma unroll
    for (int rr = 0; rr < 4; ++rr) {
        int c = g * 256 + rr * 64 + lane;
        fcc[rr] = recB[2 * c];
        km[rr] = recB[2 * c + 1].x;
    }
    __syncthreads();
    #pragma unroll 4
    for (int j = 0; j < JPW; ++j) {
        float4 fc = rb[2 * j];              // row point n
        float4 an = rb[2 * j + 1];          // {k_n, q_n, rad_n, 0}
        float lnZ = s_lnZ[wave * JPW + j];
        #pragma unroll
        for (int rr = 0; rr < 4; ++rr) {
            float dot = fc.x * fcc[rr].x + fc.y * fcc[rr].y + fc.z * fcc[rr].z;
            float d = fmaf(-2.0f, dot, fc.w) + fcc[rr].w;
            float e = __expf(an.y * km[rr] - lnZ);
            acc[rr] += (d < an.z) ? e : 0.f;
        }
    }
    #pragma unroll
    for (int rr = 0; rr < 4; ++rr) s_red[wave][rr * 64 + lane] = acc[rr];
    __syncthreads();
    if (tid < 256) {
        float s = 0.f;
        #pragma unroll
        for (int w = 0; w < 16; ++w) s += s_red[w][tid];
        part[slice * BN + g * 256 + tid] = s;
    }
}

// ---------------- P5: rs partials (row pass; ln colsum prologue) ----------
__global__ __launch_bounds__(1024, 8)
void p5_rs(const float4* __restrict__ recB, const float* __restrict__ part5,
           float* __restrict__ part) {
    __shared__ float s_red[16][256];
    __shared__ float s_lnc[SLEN];
    int tid = threadIdx.x;
    int wave = __builtin_amdgcn_readfirstlane(tid >> 6);
    int lane = tid & 63;
    int g = blockIdx.x >> 3, slice = blockIdx.x & 7;
    int b = g >> 4;
    if (tid < SLEN) {
        int gm = b * NN + slice * SLEN + tid;
        float s = 0.f;
        #pragma unroll
        for (int c = 0; c < NSLICE; ++c) s += part5[c * BN + gm];
        s_lnc[tid] = __logf(fmaxf(s, 1e-12f));
    }
    const float4* rb = recB + ((size_t)b * NN + slice * SLEN + wave * JPW) * 2;
    float4 fr[4];
    float q[4], rad[4];
    float acc[4] = {0.f, 0.f, 0.f, 0.f};
    #pragma unroll
    for (int rr = 0; rr < 4; ++rr) {
        int r = g * 256 + rr * 64 + lane;
        fr[rr] = recB[2 * r];
        float4 a = recB[2 * r + 1];
        q[rr] = a.y;
        rad[rr] = a.z;
    }
    __syncthreads();
    #pragma unroll 4
    for (int j = 0; j < JPW; ++j) {
        float4 fc = rb[2 * j];
        float km = rb[2 * j + 1].x;         // k_m
        float lnc = s_lnc[wave * JPW + j];  // ln colsum_m
        #pragma unroll
        for (int rr = 0; rr < 4; ++rr) {
            float dot = fr[rr].x * fc.x + fr[rr].y * fc.y + fr[rr].z * fc.z;
            float d = fmaf(-2.0f, dot, fr[rr].w) + fc.w;
            float e = __expf(q[rr] * km - lnc);
            acc[rr] += (d < rad[rr]) ? e : 0.f;
        }
    }
    #pragma unroll
    for (int rr = 0; rr < 4; ++rr) s_red[wave][rr * 64 + lane] = acc[rr];
    __syncthreads();
    if (tid < 256) {
        float s = 0.f;
        #pragma unroll
        for (int w = 0; w < 16; ++w) s += s_red[w][tid];
        part[slice * BN + g * 256 + tid] = s;
    }
}

// ---------------- P6: smoothed partials (col pass; lnZ+lnrs prologue) -----
__global__ __launch_bounds__(1024, 8)
void p6_smooth(const float4* __restrict__ recB, const float* __restrict__ part3,
               const float* __restrict__ part7,
               float* __restrict__ partx, float* __restrict__ party,
               float* __restrict__ partz) {
    __shared__ float s_rx[16][256];
    __shared__ float s_ry[16][256];
    __shared__ float s_rz[16][256];
    __shared__ float s_w[SLEN];
    int tid = threadIdx.x;
    int wave = __builtin_amdgcn_readfirstlane(tid >> 6);
    int lane = tid & 63;
    int g = blockIdx.x >> 3, slice = blockIdx.x & 7;
    int b = g >> 4;
    if (tid < SLEN) {
        int gn = b * NN + slice * SLEN + tid;
        float sZ = 0.f, s7 = 0.f;
        #pragma unroll
        for (int c = 0; c < NSLICE; ++c) {
            sZ += part3[c * BN + gn];
            s7 += part7[c * BN + gn];
        }
        float rs = fmaxf(s7 / sZ, 1e-12f);
        s_w[tid] = __logf(sZ) + __logf(rs);   // lnZ_n + ln rs_n
    }
    const float4* rb = recB + ((size_t)b * NN + slice * SLEN + wave * JPW) * 2;
    float4 fcc[4];
    float km[4];
    float ax[4] = {0.f, 0.f, 0.f, 0.f};
    float ay[4] = {0.f, 0.f, 0.f, 0.f};
    float az[4] = {0.f, 0.f, 0.f, 0.f};
    #pragma unroll
    for (int rr = 0; rr < 4; ++rr) {
        int c = g * 256 + rr * 64 + lane;
        fcc[rr] = recB[2 * c];
        km[rr] = recB[2 * c + 1].x;
    }
    __syncthreads();
    #pragma unroll 2
    for (int j = 0; j < JPW; ++j) {
        float4 fc = rb[2 * j];              // row point n
        float4 an = rb[2 * j + 1];          // {k_n, q_n, rad_n, 0}
        float wexp = s_w[wave * JPW + j];
        #pragma unroll
        for (int rr = 0; rr < 4; ++rr) {
            float dot = fc.x * fcc[rr].x + fc.y * fcc[rr].y + fc.z * fcc[rr].z;
            float d = fmaf(-2.0f, dot, fc.w) + fcc[rr].w;
            float w = __expf(an.y * km[rr] - wexp);
            w = (d < an.z) ? w : 0.f;
            ax[rr] += fc.x * w;
            ay[rr] += fc.y * w;
            az[rr] += fc.z * w;
        }
    }
    #pragma unroll
    for (int rr = 0; rr < 4; ++rr) {
        s_rx[wave][rr * 64 + lane] = ax[rr];
        s_ry[wave][rr * 64 + lane] = ay[rr];
        s_rz[wave][rr * 64 + lane] = az[rr];
    }
    __syncthreads();
    if (tid < 256) {
        float sx = 0.f, sy = 0.f, sz = 0.f;
        #pragma unroll
        for (int w = 0; w < 16; ++w) {
            sx += s_rx[w][tid];
            sy += s_ry[w][tid];
            sz += s_rz[w][tid];
        }
        int o = slice * BN + g * 256 + tid;
        partx[o] = sx;
        party[o] = sy;
        partz[o] = sz;
    }
}

// ---------------- K8: fused epilogue (+ smoothed/colsum reduce) -----------
__global__ void k8_final(const float* __restrict__ xyz,
                         const float* __restrict__ partx, const float* __restrict__ party,
                         const float* __restrict__ partz, const float* __restrict__ part5,
                         const int* __restrict__ idxg,
                         const float* __restrict__ w_v, const float* __restrict__ g_v, const float* __restrict__ b_v,
                         const float* __restrict__ w_pe, const float* __restrict__ b_pe,
                         const float* __restrict__ g_pe, const float* __restrict__ bb_pe,
                         const float* __restrict__ w_m1, const float* __restrict__ g_m1, const float* __restrict__ b_m1,
                         const float* __restrict__ w_m2, const float* __restrict__ g_m2, const float* __restrict__ b_m2,
                         const float* __restrict__ w_out, const float* __restrict__ g_out, const float* __restrict__ b_out,
                         float* __restrict__ out) {
    __shared__ float s_pf8[32][9];
    __shared__ float s_pf16[32][17];
    __shared__ float s_g64[32][65];
    int tid = threadIdx.x;
    int ptL = tid >> 3, o = tid & 7;
    int p = blockIdx.x * 32 + ptL;
    int b = p / NN, n = p % NN;
    const float* xb = xyz + (size_t)b * 3 * NN;
    float x = xb[n], y = xb[NN + n], z = xb[2 * NN + n];
    const float invs = rsqrtf(1.0f + 1e-5f);

    // phase A: PE 9->8, gelu(bn), max over K; thread = channel o
    float w0 = w_pe[o * 9 + 0], w1 = w_pe[o * 9 + 1], w2 = w_pe[o * 9 + 2];
    float w3 = w_pe[o * 9 + 3], w4 = w_pe[o * 9 + 4], w5 = w_pe[o * 9 + 5];
    float w6 = w_pe[o * 9 + 6], w7 = w_pe[o * 9 + 7], w8 = w_pe[o * 9 + 8];
    float bp = b_pe[o], gp = g_pe[o] * invs, bbp = bb_pe[o];
    float mx = -1e30f;
    for (int kk = 0; kk < KNBR; ++kk) {
        int j = idxg[(size_t)p * KNBR + kk];
        float gx = xb[j], gy = xb[NN + j], gz = xb[2 * NN + j];
        float dx = gx - x, dy = gy - y, dz = gz - z;
        float s = w0 * x + w1 * y + w2 * z + w3 * gx + w4 * gy + w5 * gz
                + w6 * dx + w7 * dy + w8 * dz + bp;
        s = gelu_f(s * gp + bbp);
        mx = fmaxf(mx, s);
    }
    s_pf8[ptL][o] = mx;
    __syncthreads();

    // phase B: m1 8->16, outputs o and o+8
    #pragma unroll
    for (int rr = 0; rr < 2; ++rr) {
        int r = o + rr * 8;
        const float* w = w_m1 + r * 8;
        float s = 0.f;
        #pragma unroll
        for (int c = 0; c < 8; ++c) s += w[c] * s_pf8[ptL][c];
        s_pf16[ptL][r] = gelu_f(s * (g_m1[r] * invs) + b_m1[r]);
    }
    __syncthreads();

    // phase C: m2 16->64 + value conv, gelu(v+pos); channels o*8..o*8+7
    float cs = 0.f, sx = 0.f, sy = 0.f, sz = 0.f;
    #pragma unroll
    for (int c = 0; c < NSLICE; ++c) {
        cs += part5[c * BN + p];
        sx += partx[c * BN + p];
        sy += party[c * BN + p];
        sz += partz[c * BN + p];
    }
    float inv = 1.0f / fmaxf(cs, 1e-12f);
    float vx = sx * inv - x, vy = sy * inv - y, vz = sz * inv - z;
    #pragma unroll
    for (int i = 0; i < 8; ++i) {
        int ch = o * 8 + i;
        const float* wm = w_m2 + ch * 16;
        float pos = 0.f;
        #pragma unroll
        for (int c = 0; c < 16; ++c) pos += wm[c] * s_pf16[ptL][c];
        pos = pos * (g_m2[ch] * invs) + b_m2[ch];
        const float* wv = w_v + ch * 6;
        float vv = wv[0] * vx + wv[1] * vy + wv[2] * vz + wv[3] * x + wv[4] * y + wv[5] * z;
        vv = vv * (g_v[ch] * invs) + b_v[ch];
        s_g64[ptL][ch] = gelu_f(vv + pos);
    }
    __syncthreads();

    // phase D: out conv 64->32 + BN; outputs o*4..o*4+3
    #pragma unroll
    for (int i = 0; i < 4; ++i) {
        int ch = o * 4 + i;
        const float* w = w_out + ch * 64;
        float s = 0.f;
        #pragma unroll
        for (int c = 0; c < 64; ++c) s += w[c] * s_g64[ptL][c];
        out[((size_t)b * 32 + ch) * NN + n] = s * (g_out[ch] * invs) + b_out[ch];
    }
}

extern "C" void kernel_launch(void* const* d_in, const int* in_sizes, int n_in,
                              void* d_out, int out_size, void* d_ws, size_t ws_size,
                              hipStream_t stream) {
    const float* xyz  = (const float*)d_in[0];
    const float* w_q  = (const float*)d_in[1];
    const float* g_q  = (const float*)d_in[2];
    const float* b_q  = (const float*)d_in[3];
    const float* w_k  = (const float*)d_in[4];
    const float* g_k  = (const float*)d_in[5];
    const float* b_k  = (const float*)d_in[6];
    const float* w_v  = (const float*)d_in[7];
    const float* g_v  = (const float*)d_in[8];
    const float* b_v  = (const float*)d_in[9];
    const float* w_pe = (const float*)d_in[10];
    const float* b_pe = (const float*)d_in[11];
    const float* g_pe = (const float*)d_in[12];
    const float* bb_pe= (const float*)d_in[13];
    const float* w_m1 = (const float*)d_in[14];
    const float* g_m1 = (const float*)d_in[15];
    const float* b_m1 = (const float*)d_in[16];
    const float* w_m2 = (const float*)d_in[17];
    const float* g_m2 = (const float*)d_in[18];
    const float* b_m2 = (const float*)d_in[19];
    const float* w_out= (const float*)d_in[20];
    const float* g_out= (const float*)d_in[21];
    const float* b_out= (const float*)d_in[22];

    float* ws = (float*)d_ws;
    float4* recB   = (float4*)ws;                      // 8BN
    int*    idxg   = (int*)   (ws + (size_t)8  * BN);  // 20BN
    float*  part1  = ws + (size_t)28 * BN;             // 8BN
    float*  part3  = ws + (size_t)36 * BN;             // 8BN
    float*  part5  = ws + (size_t)44 * BN;             // 8BN
    float*  part7  = ws + (size_t)52 * BN;             // 8BN
    float*  partx  = ws + (size_t)60 * BN;             // 8BN
    float*  party  = ws + (size_t)68 * BN;             // 8BN
    float*  partz  = ws + (size_t)76 * BN;             // 8BN

    const int PB = (BN / 256) * NSLICE;   // 512 blocks of 1024 threads

    p1_kd<<<PB, 1024, 0, stream>>>(xyz, part1);
    k2_radius<<<BB, 1024, 0, stream>>>(part1, xyz, w_q, g_q, b_q, w_k, g_k, b_k, recB);
    p3_Zk7<<<PB, 1024, 0, stream>>>(recB, part3, idxg);
    p4_colsum<<<PB, 1024, 0, stream>>>(recB, part3, part5);
    p5_rs<<<PB, 1024, 0, stream>>>(recB, part5, part7);
    p6_smooth<<<PB, 1024, 0, stream>>>(recB, part3, part7, partx, party, partz);
    k8_final<<<BN / 32, 256, 0, stream>>>(xyz, partx, party, partz, part5, idxg,
                                          w_v, g_v, b_v,
                                          w_pe, b_pe, g_pe, bb_pe,
                                          w_m1, g_m1, b_m1,
                                          w_m2, g_m2, b_m2,
                                          w_out, g_out, b_out,
                                          (float*)d_out);
}

// Round 9
// 233.614 us; speedup vs baseline: 1.2405x; 1.0476x over previous
//
#include <hip/hip_runtime.h>
#include <math.h>

#define BB 4
#define NN 4096
#define KNBR 20
#define BN (BB * NN)
#define NSLICE 8
#define SLEN (NN / NSLICE)     // 512 summed indices per slice
#define JPW (SLEN / 16)        // 32 summed indices per wave

#define LOG2E 1.44269504088896340736f

typedef __attribute__((ext_vector_type(2))) float v2f;

__device__ __forceinline__ v2f fma2(v2f a, v2f b, v2f c) {
    return __builtin_elementwise_fma(a, b, c);
}
__device__ __forceinline__ v2f splat2(float s) { v2f r; r.x = s; r.y = s; return r; }

__device__ __forceinline__ float gelu_f(float x) {
    return 0.5f * x * (1.0f + erff(x * 0.70710678118654752440f));
}

// Canonical point record: identical instruction sequence everywhere.
__device__ __forceinline__ float4 mkrec(const float* __restrict__ xb, int n) {
    float x = xb[n], y = xb[NN + n], z = xb[2 * NN + n];
    float sq = fmaf(x, x, fmaf(y, y, z * z));
    return make_float4(x, y, z, sq);
}

// ---------------- K0: pts4 = {x,y,z,sq} -----------------------------------
__global__ void k0_prep(const float* __restrict__ xyz, float4* __restrict__ pts4) {
    int t = blockIdx.x * blockDim.x + threadIdx.x;
    if (t >= BN) return;
    int b = t / NN, n = t % NN;
    pts4[t] = mkrec(xyz + (size_t)b * 3 * NN, n);
}

// Pass decomposition: grid = 64 output-groups (256 pts) x 8 sum-slices (512).
// Block 1024 thr = 16 waves; wave w handles summed indices [w*32, w*32+32).
// Lane handles 4 output rows as 2x float2 packs. Uniform summed loads.

// ---------------- P1: kd partials ----------------------------------------
__global__ __launch_bounds__(1024, 8)
void p1_kd(const float4* __restrict__ pts4, float* __restrict__ part) {
    __shared__ float s_red[16][256];
    int tid = threadIdx.x;
    int wave = __builtin_amdgcn_readfirstlane(tid >> 6);
    int lane = tid & 63;
    int g = blockIdx.x >> 3, slice = blockIdx.x & 7;
    int b = g >> 4;
    const float4* rb = pts4 + (size_t)b * NN + slice * SLEN + wave * JPW;
    v2f frx[2], fry[2], frz[2], frw[2];
    v2f acc[2] = {splat2(0.f), splat2(0.f)};
    #pragma unroll
    for (int h = 0; h < 2; ++h) {
        float4 r0 = pts4[g * 256 + (2 * h) * 64 + lane];
        float4 r1 = pts4[g * 256 + (2 * h + 1) * 64 + lane];
        frx[h].x = r0.x; frx[h].y = r1.x;
        fry[h].x = r0.y; fry[h].y = r1.y;
        frz[h].x = r0.z; frz[h].y = r1.z;
        frw[h].x = r0.w; frw[h].y = r1.w;
    }
    const v2f m2 = splat2(-2.0f);
    const float C1 = -50.0f * LOG2E;
    #pragma unroll 4
    for (int j = 0; j < JPW; ++j) {
        float4 fc = rb[j];
        #pragma unroll
        for (int h = 0; h < 2; ++h) {
            v2f dot = frx[h] * fc.x + fry[h] * fc.y + frz[h] * fc.z;
            v2f d = fma2(m2, dot, frw[h]) + fc.w;
            v2f arg = d * C1;
            acc[h].x += __builtin_amdgcn_exp2f(arg.x);
            acc[h].y += __builtin_amdgcn_exp2f(arg.y);
        }
    }
    #pragma unroll
    for (int h = 0; h < 2; ++h) {
        s_red[wave][(2 * h) * 64 + lane] = acc[h].x;
        s_red[wave][(2 * h + 1) * 64 + lane] = acc[h].y;
    }
    __syncthreads();
    if (tid < 256) {
        float s = 0.f;
        #pragma unroll
        for (int w = 0; w < 16; ++w) s += s_red[w][tid];
        part[slice * BN + g * 256 + tid] = s;
    }
}

// ---------------- K2: reduce kd + per-batch max; build recB ---------------
// recB[2n] = {x,y,z,sq}; recB[2n+1] = {k, q, rad, 0}
__global__ void k2_radius(const float* __restrict__ part, const float4* __restrict__ pts4,
                          const float* __restrict__ w_q, const float* __restrict__ g_q, const float* __restrict__ b_q,
                          const float* __restrict__ w_k, const float* __restrict__ g_k, const float* __restrict__ b_k,
                          float4* __restrict__ recB) {
    int b = blockIdx.x;
    int t = threadIdx.x;   // 1024
    const float invs = rsqrtf(1.0f + 1e-5f);
    float kdv[4];
    float mx = -1e30f;
    #pragma unroll
    for (int j = 0; j < 4; ++j) {
        int n = b * NN + j * 1024 + t;
        float s = 0.f;
        #pragma unroll
        for (int c = 0; c < NSLICE; ++c) s += part[c * BN + n];
        kdv[j] = s;
        mx = fmaxf(mx, s);
    }
    __shared__ float red[1024];
    red[t] = mx;
    __syncthreads();
    for (int s = 512; s > 0; s >>= 1) {
        if (t < s) red[t] = fmaxf(red[t], red[t + s]);
        __syncthreads();
    }
    float kmax = red[0];
    #pragma unroll
    for (int j = 0; j < 4; ++j) {
        int n = b * NN + j * 1024 + t;
        float rad = 0.1f + 0.1f * (kdv[j] / (kmax + 1e-9f));
        float4 r = pts4[n];
        float qr = r.x * (w_q[0] + w_q[3]) + r.y * (w_q[1] + w_q[4]) + r.z * (w_q[2] + w_q[5]);
        float kr = r.x * (w_k[0] + w_k[3]) + r.y * (w_k[1] + w_k[4]) + r.z * (w_k[2] + w_k[5]);
        float q = qr * (g_q[0] * invs) + b_q[0];
        float k = kr * (g_k[0] * invs) + b_k[0];
        recB[2 * n] = r;
        recB[2 * n + 1] = make_float4(k, q, rad, 0.f);
    }
}

// ---------------- P3: Z partials + k7 neighbor scan ----------------------
__global__ __launch_bounds__(1024, 8)
void p3_Zk7(const float4* __restrict__ recB, float* __restrict__ part,
            int* __restrict__ idxg) {
    __shared__ float s_red[16][256];
    int tid = threadIdx.x;
    int wave = __builtin_amdgcn_readfirstlane(tid >> 6);
    int lane = tid & 63;
    int g = blockIdx.x >> 3, slice = blockIdx.x & 7;
    int b = g >> 4;
    const float4* rb = recB + ((size_t)b * NN + slice * SLEN + wave * JPW) * 2;
    v2f frx[2], fry[2], frz[2], frw[2], ql2[2], rad[2];
    v2f acc[2] = {splat2(0.f), splat2(0.f)};
    #pragma unroll
    for (int h = 0; h < 2; ++h) {
        int r0i = g * 256 + (2 * h) * 64 + lane;
        int r1i = g * 256 + (2 * h + 1) * 64 + lane;
        float4 r0 = recB[2 * r0i], a0 = recB[2 * r0i + 1];
        float4 r1 = recB[2 * r1i], a1 = recB[2 * r1i + 1];
        frx[h].x = r0.x; frx[h].y = r1.x;
        fry[h].x = r0.y; fry[h].y = r1.y;
        frz[h].x = r0.z; frz[h].y = r1.z;
        frw[h].x = r0.w; frw[h].y = r1.w;
        ql2[h].x = a0.y * LOG2E; ql2[h].y = a1.y * LOG2E;
        rad[h].x = a0.z; rad[h].y = a1.z;
    }
    const v2f m2 = splat2(-2.0f);
    #pragma unroll 4
    for (int j = 0; j < JPW; ++j) {
        float4 fc = rb[2 * j];
        float4 an = rb[2 * j + 1];          // {k, q, rad, 0}
        #pragma unroll
        for (int h = 0; h < 2; ++h) {
            v2f dot = frx[h] * fc.x + fry[h] * fc.y + frz[h] * fc.z;
            v2f d = fma2(m2, dot, frw[h]) + fc.w;
            v2f arg = ql2[h] * an.x;
            float e0 = __builtin_amdgcn_exp2f(arg.x);
            float e1 = __builtin_amdgcn_exp2f(arg.y);
            acc[h].x += (d.x < rad[h].x) ? e0 : 0.f;
            acc[h].y += (d.y < rad[h].y) ? e1 : 0.f;
        }
    }
    #pragma unroll
    for (int h = 0; h < 2; ++h) {
        s_red[wave][(2 * h) * 64 + lane] = acc[h].x;
        s_red[wave][(2 * h + 1) * 64 + lane] = acc[h].y;
    }
    __syncthreads();
    if (tid < 256) {
        float s = 0.f;
        #pragma unroll
        for (int w = 0; w < 16; ++w) s += s_red[w][tid];
        part[slice * BN + g * 256 + tid] = s;
    }
    // k7: first-20-by-index in-ball neighbors; 2 rows per wave
    int gw = blockIdx.x * 16 + wave;
    for (int rr = 0; rr < 2; ++rr) {
        int row7 = gw * 2 + rr;
        int b7 = row7 / NN;
        const float4* p7 = recB + (size_t)b7 * NN * 2;
        float4 f7 = recB[2 * row7];
        float rad7 = recB[2 * row7 + 1].z;
        int total = 0, firstm = 0;
        bool have = false;
        unsigned long long lmask = (1ULL << lane) - 1ULL;
        for (int i = 0; i < NN / 64 && total < KNBR; ++i) {
            int m = i * 64 + lane;
            float4 fc = p7[2 * m];
            float dot = f7.x * fc.x + f7.y * fc.y + f7.z * fc.z;
            float d = fmaf(-2.0f, dot, f7.w) + fc.w;
            bool inb = !(d > rad7);   // dist <= radius
            unsigned long long mask = __ballot(inb);
            if (!have && mask != 0ULL) {
                int src7 = __ffsll(mask) - 1;
                firstm = __shfl(m, src7);
                have = true;
            }
            int pos = total + (int)__popcll(mask & lmask);
            if (inb && pos < KNBR) idxg[(size_t)row7 * KNBR + pos] = m;
            total += (int)__popcll(mask);
        }
        if (total < KNBR && lane >= total && lane < KNBR)
            idxg[(size_t)row7 * KNBR + lane] = firstm;
    }
}

// ---------------- P4: colsum partials (col pass; log2Z prologue) ----------
__global__ __launch_bounds__(1024, 8)
void p4_colsum(const float4* __restrict__ recB, const float* __restrict__ part3,
               float* __restrict__ part) {
    __shared__ float s_red[16][256];
    __shared__ float s_lnZ[SLEN];
    int tid = threadIdx.x;
    int wave = __builtin_amdgcn_readfirstlane(tid >> 6);
    int lane = tid & 63;
    int g = blockIdx.x >> 3, slice = blockIdx.x & 7;
    int b = g >> 4;
    if (tid < SLEN) {
        int gn = b * NN + slice * SLEN + tid;
        float s = 0.f;
        #pragma unroll
        for (int c = 0; c < NSLICE; ++c) s += part3[c * BN + gn];
        s_lnZ[tid] = __log2f(s);
    }
    const float4* rb = recB + ((size_t)b * NN + slice * SLEN + wave * JPW) * 2;
    v2f fcx[2], fcy[2], fcz[2], fcw[2], km2[2];
    v2f acc[2] = {splat2(0.f), splat2(0.f)};
    #pragma unroll
    for (int h = 0; h < 2; ++h) {
        int c0 = g * 256 + (2 * h) * 64 + lane;
        int c1 = g * 256 + (2 * h + 1) * 64 + lane;
        float4 r0 = recB[2 * c0], a0 = recB[2 * c0 + 1];
        float4 r1 = recB[2 * c1], a1 = recB[2 * c1 + 1];
        fcx[h].x = r0.x; fcx[h].y = r1.x;
        fcy[h].x = r0.y; fcy[h].y = r1.y;
        fcz[h].x = r0.z; fcz[h].y = r1.z;
        fcw[h].x = r0.w; fcw[h].y = r1.w;
        km2[h].x = a0.x * LOG2E; km2[h].y = a1.x * LOG2E;
    }
    __syncthreads();
    const v2f m2 = splat2(-2.0f);
    #pragma unroll 4
    for (int j = 0; j < JPW; ++j) {
        float4 fc = rb[2 * j];              // row point n
        float4 an = rb[2 * j + 1];          // {k_n, q_n, rad_n, 0}
        float lnZ2 = s_lnZ[wave * JPW + j];
        #pragma unroll
        for (int h = 0; h < 2; ++h) {
            v2f dot = fcx[h] * fc.x + fcy[h] * fc.y + fcz[h] * fc.z;
            v2f d = fma2(m2, dot, splat2(fc.w)) + fcw[h];
            v2f arg = fma2(splat2(an.y), km2[h], splat2(-lnZ2));
            float e0 = __builtin_amdgcn_exp2f(arg.x);
            float e1 = __builtin_amdgcn_exp2f(arg.y);
            acc[h].x += (d.x < an.z) ? e0 : 0.f;
            acc[h].y += (d.y < an.z) ? e1 : 0.f;
        }
    }
    #pragma unroll
    for (int h = 0; h < 2; ++h) {
        s_red[wave][(2 * h) * 64 + lane] = acc[h].x;
        s_red[wave][(2 * h + 1) * 64 + lane] = acc[h].y;
    }
    __syncthreads();
    if (tid < 256) {
        float s = 0.f;
        #pragma unroll
        for (int w = 0; w < 16; ++w) s += s_red[w][tid];
        part[slice * BN + g * 256 + tid] = s;
    }
}

// ---------------- P5: rs partials (row pass; log2 colsum prologue) --------
__global__ __launch_bounds__(1024, 8)
void p5_rs(const float4* __restrict__ recB, const float* __restrict__ part5,
           float* __restrict__ part) {
    __shared__ float s_red[16][256];
    __shared__ float s_lnc[SLEN];
    int tid = threadIdx.x;
    int wave = __builtin_amdgcn_readfirstlane(tid >> 6);
    int lane = tid & 63;
    int g = blockIdx.x >> 3, slice = blockIdx.x & 7;
    int b = g >> 4;
    if (tid < SLEN) {
        int gm = b * NN + slice * SLEN + tid;
        float s = 0.f;
        #pragma unroll
        for (int c = 0; c < NSLICE; ++c) s += part5[c * BN + gm];
        s_lnc[tid] = __log2f(fmaxf(s, 1e-12f));
    }
    const float4* rb = recB + ((size_t)b * NN + slice * SLEN + wave * JPW) * 2;
    v2f frx[2], fry[2], frz[2], frw[2], ql2[2], rad[2];
    v2f acc[2] = {splat2(0.f), splat2(0.f)};
    #pragma unroll
    for (int h = 0; h < 2; ++h) {
        int r0i = g * 256 + (2 * h) * 64 + lane;
        int r1i = g * 256 + (2 * h + 1) * 64 + lane;
        float4 r0 = recB[2 * r0i], a0 = recB[2 * r0i + 1];
        float4 r1 = recB[2 * r1i], a1 = recB[2 * r1i + 1];
        frx[h].x = r0.x; frx[h].y = r1.x;
        fry[h].x = r0.y; fry[h].y = r1.y;
        frz[h].x = r0.z; frz[h].y = r1.z;
        frw[h].x = r0.w; frw[h].y = r1.w;
        ql2[h].x = a0.y * LOG2E; ql2[h].y = a1.y * LOG2E;
        rad[h].x = a0.z; rad[h].y = a1.z;
    }
    __syncthreads();
    const v2f m2 = splat2(-2.0f);
    #pragma unroll 4
    for (int j = 0; j < JPW; ++j) {
        float4 fc = rb[2 * j];
        float km = rb[2 * j + 1].x;         // k_m
        float lnc2 = s_lnc[wave * JPW + j]; // log2 colsum_m
        #pragma unroll
        for (int h = 0; h < 2; ++h) {
            v2f dot = frx[h] * fc.x + fry[h] * fc.y + frz[h] * fc.z;
            v2f d = fma2(m2, dot, frw[h]) + fc.w;
            v2f arg = fma2(splat2(km), ql2[h], splat2(-lnc2));
            float e0 = __builtin_amdgcn_exp2f(arg.x);
            float e1 = __builtin_amdgcn_exp2f(arg.y);
            acc[h].x += (d.x < rad[h].x) ? e0 : 0.f;
            acc[h].y += (d.y < rad[h].y) ? e1 : 0.f;
        }
    }
    #pragma unroll
    for (int h = 0; h < 2; ++h) {
        s_red[wave][(2 * h) * 64 + lane] = acc[h].x;
        s_red[wave][(2 * h + 1) * 64 + lane] = acc[h].y;
    }
    __syncthreads();
    if (tid < 256) {
        float s = 0.f;
        #pragma unroll
        for (int w = 0; w < 16; ++w) s += s_red[w][tid];
        part[slice * BN + g * 256 + tid] = s;
    }
}

// ---------------- P6: smoothed partials (col pass; prologue) --------------
__global__ __launch_bounds__(1024, 8)
void p6_smooth(const float4* __restrict__ recB, const float* __restrict__ part3,
               const float* __restrict__ part7,
               float* __restrict__ partx, float* __restrict__ party,
               float* __restrict__ partz) {
    __shared__ float s_rx[16][256];
    __shared__ float s_ry[16][256];
    __shared__ float s_rz[16][256];
    __shared__ float s_w[SLEN];
    int tid = threadIdx.x;
    int wave = __builtin_amdgcn_readfirstlane(tid >> 6);
    int lane = tid & 63;
    int g = blockIdx.x >> 3, slice = blockIdx.x & 7;
    int b = g >> 4;
    if (tid < SLEN) {
        int gn = b * NN + slice * SLEN + tid;
        float sZ = 0.f, s7 = 0.f;
        #pragma unroll
        for (int c = 0; c < NSLICE; ++c) {
            sZ += part3[c * BN + gn];
            s7 += part7[c * BN + gn];
        }
        float rs = fmaxf(s7 / sZ, 1e-12f);
        s_w[tid] = __log2f(sZ) + __log2f(rs);   // log2(Z_n) + log2(rs_n)
    }
    const float4* rb = recB + ((size_t)b * NN + slice * SLEN + wave * JPW) * 2;
    v2f fcx[2], fcy[2], fcz[2], fcw[2], km2[2];
    v2f ax[2] = {splat2(0.f), splat2(0.f)};
    v2f ay[2] = {splat2(0.f), splat2(0.f)};
    v2f az[2] = {splat2(0.f), splat2(0.f)};
    #pragma unroll
    for (int h = 0; h < 2; ++h) {
        int c0 = g * 256 + (2 * h) * 64 + lane;
        int c1 = g * 256 + (2 * h + 1) * 64 + lane;
        float4 r0 = recB[2 * c0], a0 = recB[2 * c0 + 1];
        float4 r1 = recB[2 * c1], a1 = recB[2 * c1 + 1];
        fcx[h].x = r0.x; fcx[h].y = r1.x;
        fcy[h].x = r0.y; fcy[h].y = r1.y;
        fcz[h].x = r0.z; fcz[h].y = r1.z;
        fcw[h].x = r0.w; fcw[h].y = r1.w;
        km2[h].x = a0.x * LOG2E; km2[h].y = a1.x * LOG2E;
    }
    __syncthreads();
    const v2f m2 = splat2(-2.0f);
    #pragma unroll 2
    for (int j = 0; j < JPW; ++j) {
        float4 fc = rb[2 * j];              // row point n
        float4 an = rb[2 * j + 1];          // {k_n, q_n, rad_n, 0}
        float w2j = s_w[wave * JPW + j];
        #pragma unroll
        for (int h = 0; h < 2; ++h) {
            v2f dot = fcx[h] * fc.x + fcy[h] * fc.y + fcz[h] * fc.z;
            v2f d = fma2(m2, dot, splat2(fc.w)) + fcw[h];
            v2f arg = fma2(splat2(an.y), km2[h], splat2(-w2j));
            float e0 = __builtin_amdgcn_exp2f(arg.x);
            float e1 = __builtin_amdgcn_exp2f(arg.y);
            v2f w;
            w.x = (d.x < an.z) ? e0 : 0.f;
            w.y = (d.y < an.z) ? e1 : 0.f;
            ax[h] = fma2(splat2(fc.x), w, ax[h]);
            ay[h] = fma2(splat2(fc.y), w, ay[h]);
            az[h] = fma2(splat2(fc.z), w, az[h]);
        }
    }
    #pragma unroll
    for (int h = 0; h < 2; ++h) {
        s_rx[wave][(2 * h) * 64 + lane] = ax[h].x;
        s_rx[wave][(2 * h + 1) * 64 + lane] = ax[h].y;
        s_ry[wave][(2 * h) * 64 + lane] = ay[h].x;
        s_ry[wave][(2 * h + 1) * 64 + lane] = ay[h].y;
        s_rz[wave][(2 * h) * 64 + lane] = az[h].x;
        s_rz[wave][(2 * h + 1) * 64 + lane] = az[h].y;
    }
    __syncthreads();
    if (tid < 256) {
        float sx = 0.f, sy = 0.f, sz = 0.f;
        #pragma unroll
        for (int w = 0; w < 16; ++w) {
            sx += s_rx[w][tid];
            sy += s_ry[w][tid];
            sz += s_rz[w][tid];
        }
        int o = slice * BN + g * 256 + tid;
        partx[o] = sx;
        party[o] = sy;
        partz[o] = sz;
    }
}

// ---------------- K8: fused epilogue (+ smoothed/colsum reduce) -----------
__global__ void k8_final(const float* __restrict__ xyz,
                         const float* __restrict__ partx, const float* __restrict__ party,
                         const float* __restrict__ partz, const float* __restrict__ part5,
                         const int* __restrict__ idxg,
                         const float* __restrict__ w_v, const float* __restrict__ g_v, const float* __restrict__ b_v,
                         const float* __restrict__ w_pe, const float* __restrict__ b_pe,
                         const float* __restrict__ g_pe, const float* __restrict__ bb_pe,
                         const float* __restrict__ w_m1, const float* __restrict__ g_m1, const float* __restrict__ b_m1,
                         const float* __restrict__ w_m2, const float* __restrict__ g_m2, const float* __restrict__ b_m2,
                         const float* __restrict__ w_out, const float* __restrict__ g_out, const float* __restrict__ b_out,
                         float* __restrict__ out) {
    __shared__ float s_pf8[32][9];
    __shared__ float s_pf16[32][17];
    __shared__ float s_g64[32][65];
    int tid = threadIdx.x;
    int ptL = tid >> 3, o = tid & 7;
    int p = blockIdx.x * 32 + ptL;
    int b = p / NN, n = p % NN;
    const float* xb = xyz + (size_t)b * 3 * NN;
    float x = xb[n], y = xb[NN + n], z = xb[2 * NN + n];
    const float invs = rsqrtf(1.0f + 1e-5f);

    // phase A: PE 9->8, gelu(bn), max over K; thread = channel o
    float w0 = w_pe[o * 9 + 0], w1 = w_pe[o * 9 + 1], w2 = w_pe[o * 9 + 2];
    float w3 = w_pe[o * 9 + 3], w4 = w_pe[o * 9 + 4], w5 = w_pe[o * 9 + 5];
    float w6 = w_pe[o * 9 + 6], w7 = w_pe[o * 9 + 7], w8 = w_pe[o * 9 + 8];
    float bp = b_pe[o], gp = g_pe[o] * invs, bbp = bb_pe[o];
    float mx = -1e30f;
    for (int kk = 0; kk < KNBR; ++kk) {
        int j = idxg[(size_t)p * KNBR + kk];
        float gx = xb[j], gy = xb[NN + j], gz = xb[2 * NN + j];
        float dx = gx - x, dy = gy - y, dz = gz - z;
        float s = w0 * x + w1 * y + w2 * z + w3 * gx + w4 * gy + w5 * gz
                + w6 * dx + w7 * dy + w8 * dz + bp;
        s = gelu_f(s * gp + bbp);
        mx = fmaxf(mx, s);
    }
    s_pf8[ptL][o] = mx;
    __syncthreads();

    // phase B: m1 8->16, outputs o and o+8
    #pragma unroll
    for (int rr = 0; rr < 2; ++rr) {
        int r = o + rr * 8;
        const float* w = w_m1 + r * 8;
        float s = 0.f;
        #pragma unroll
        for (int c = 0; c < 8; ++c) s += w[c] * s_pf8[ptL][c];
        s_pf16[ptL][r] = gelu_f(s * (g_m1[r] * invs) + b_m1[r]);
    }
    __syncthreads();

    // phase C: m2 16->64 + value conv, gelu(v+pos); channels o*8..o*8+7
    float cs = 0.f, sx = 0.f, sy = 0.f, sz = 0.f;
    #pragma unroll
    for (int c = 0; c < NSLICE; ++c) {
        cs += part5[c * BN + p];
        sx += partx[c * BN + p];
        sy += party[c * BN + p];
        sz += partz[c * BN + p];
    }
    float inv = 1.0f / fmaxf(cs, 1e-12f);
    float vx = sx * inv - x, vy = sy * inv - y, vz = sz * inv - z;
    #pragma unroll
    for (int i = 0; i < 8; ++i) {
        int ch = o * 8 + i;
        const float* wm = w_m2 + ch * 16;
        float pos = 0.f;
        #pragma unroll
        for (int c = 0; c < 16; ++c) pos += wm[c] * s_pf16[ptL][c];
        pos = pos * (g_m2[ch] * invs) + b_m2[ch];
        const float* wv = w_v + ch * 6;
        float vv = wv[0] * vx + wv[1] * vy + wv[2] * vz + wv[3] * x + wv[4] * y + wv[5] * z;
        vv = vv * (g_v[ch] * invs) + b_v[ch];
        s_g64[ptL][ch] = gelu_f(vv + pos);
    }
    __syncthreads();

    // phase D: out conv 64->32 + BN; outputs o*4..o*4+3
    #pragma unroll
    for (int i = 0; i < 4; ++i) {
        int ch = o * 4 + i;
        const float* w = w_out + ch * 64;
        float s = 0.f;
        #pragma unroll
        for (int c = 0; c < 64; ++c) s += w[c] * s_g64[ptL][c];
        out[((size_t)b * 32 + ch) * NN + n] = s * (g_out[ch] * invs) + b_out[ch];
    }
}

extern "C" void kernel_launch(void* const* d_in, const int* in_sizes, int n_in,
                              void* d_out, int out_size, void* d_ws, size_t ws_size,
                              hipStream_t stream) {
    const float* xyz  = (const float*)d_in[0];
    const float* w_q  = (const float*)d_in[1];
    const float* g_q  = (const float*)d_in[2];
    const float* b_q  = (const float*)d_in[3];
    const float* w_k  = (const float*)d_in[4];
    const float* g_k  = (const float*)d_in[5];
    const float* b_k  = (const float*)d_in[6];
    const float* w_v  = (const float*)d_in[7];
    const float* g_v  = (const float*)d_in[8];
    const float* b_v  = (const float*)d_in[9];
    const float* w_pe = (const float*)d_in[10];
    const float* b_pe = (const float*)d_in[11];
    const float* g_pe = (const float*)d_in[12];
    const float* bb_pe= (const float*)d_in[13];
    const float* w_m1 = (const float*)d_in[14];
    const float* g_m1 = (const float*)d_in[15];
    const float* b_m1 = (const float*)d_in[16];
    const float* w_m2 = (const float*)d_in[17];
    const float* g_m2 = (const float*)d_in[18];
    const float* b_m2 = (const float*)d_in[19];
    const float* w_out= (const float*)d_in[20];
    const float* g_out= (const float*)d_in[21];
    const float* b_out= (const float*)d_in[22];

    float* ws = (float*)d_ws;
    float4* pts4   = (float4*)ws;                      // 4BN
    float4* recB   = (float4*)(ws + (size_t)4  * BN);  // 8BN
    int*    idxg   = (int*)   (ws + (size_t)12 * BN);  // 20BN
    float*  part1  = ws + (size_t)32 * BN;             // 8BN
    float*  part3  = ws + (size_t)40 * BN;             // 8BN
    float*  part5  = ws + (size_t)48 * BN;             // 8BN
    float*  part7  = ws + (size_t)56 * BN;             // 8BN
    float*  partx  = ws + (size_t)64 * BN;             // 8BN
    float*  party  = ws + (size_t)72 * BN;             // 8BN
    float*  partz  = ws + (size_t)80 * BN;             // 8BN

    const int PB = (BN / 256) * NSLICE;   // 512 blocks of 1024 threads

    k0_prep<<<BN / 256, 256, 0, stream>>>(xyz, pts4);
    p1_kd<<<PB, 1024, 0, stream>>>(pts4, part1);
    k2_radius<<<BB, 1024, 0, stream>>>(part1, pts4, w_q, g_q, b_q, w_k, g_k, b_k, recB);
    p3_Zk7<<<PB, 1024, 0, stream>>>(recB, part3, idxg);
    p4_colsum<<<PB, 1024, 0, stream>>>(recB, part3, part5);
    p5_rs<<<PB, 1024, 0, stream>>>(recB, part5, part7);
    p6_smooth<<<PB, 1024, 0, stream>>>(recB, part3, part7, partx, party, partz);
    k8_final<<<BN / 32, 256, 0, stream>>>(xyz, partx, party, partz, part5, idxg,
                                          w_v, g_v, b_v,
                                          w_pe, b_pe, g_pe, bb_pe,
                                          w_m1, g_m1, b_m1,
                                          w_m2, g_m2, b_m2,
                                          w_out, g_out, b_out,
                                          (float*)d_out);
}